// Round 8
// baseline (1718.432 us; speedup 1.0000x reference)
//
#include <hip/hip_runtime.h>
#include <hip/hip_bf16.h>

// ---------------------------------------------------------------------------
// Generator_58737972740271.  R8: R7 mega-kernel with the workspace-layout bug
// fixed (a.whi / a.wlo were never assigned -> wild device writes -> GPU page
// fault).  Single persistent kernel, 512 blocks x 256 threads (2 blocks/CU,
// co-resident by construction), device-scope atomic grid barriers replacing
// 21 dispatches.  Phase bodies identical to the R6 kernels (absmax 1.5e-4).
// ---------------------------------------------------------------------------

typedef __hip_bfloat16 bf16;
typedef unsigned short ushort_t;
typedef float v4f __attribute__((ext_vector_type(4)));
typedef short v8s __attribute__((ext_vector_type(8)));
#define MFMA_BF16 __builtin_amdgcn_mfma_f32_16x16x32_bf16

#define NB 32
#define NN 1024
#define NBLK 512
#define TPB  256

__device__ __forceinline__ float ldin(const void* p, size_t i, int f32){
    return f32 ? ((const float*)p)[i] : __bfloat162float(((const bf16*)p)[i]);
}
__device__ __forceinline__ float bf2f(ushort_t u){
    return __uint_as_float((unsigned)u << 16);
}
__device__ __forceinline__ ushort_t f2bf(float v){
    bf16 h = __float2bfloat16(v);
    ushort_t s; __builtin_memcpy(&s, &h, 2);
    return s;
}
__device__ __forceinline__ void unpack8(uint4 v, float* f){
    f[0] = __uint_as_float(v.x << 16);
    f[1] = __uint_as_float(v.x & 0xffff0000u);
    f[2] = __uint_as_float(v.y << 16);
    f[3] = __uint_as_float(v.y & 0xffff0000u);
    f[4] = __uint_as_float(v.z << 16);
    f[5] = __uint_as_float(v.z & 0xffff0000u);
    f[6] = __uint_as_float(v.w << 16);
    f[7] = __uint_as_float(v.w & 0xffff0000u);
}
__device__ __forceinline__ void unpack4(uint2 v, float* f){
    f[0] = __uint_as_float(v.x << 16);
    f[1] = __uint_as_float(v.x & 0xffff0000u);
    f[2] = __uint_as_float(v.y << 16);
    f[3] = __uint_as_float(v.y & 0xffff0000u);
}

// grid barrier: monotone counters, one index per sync point, arena pre-zeroed.
__device__ __forceinline__ void gbar(unsigned* bar, int idx){
    __syncthreads();
    if (threadIdx.x == 0){
        __threadfence();
        __hip_atomic_fetch_add(&bar[idx], 1u, __ATOMIC_ACQ_REL, __HIP_MEMORY_SCOPE_AGENT);
        int guard = 0;
        while (__hip_atomic_load(&bar[idx], __ATOMIC_ACQUIRE, __HIP_MEMORY_SCOPE_AGENT)
               < (unsigned)NBLK){
            __builtin_amdgcn_s_sleep(1);
            if (++guard > (1 << 24)) break;   // bail -> wrong answer, never hang
        }
        __threadfence();
    }
    __syncthreads();
}

struct MegaArgs {
    const void* input;
    const void* pw[11]; int pK[11], pO[11], poff[11];
    const void* e1b; const void* bn1g; const void* bn1b;
    const void* e2b; const void* bn2g; const void* bn2b;
    const void* e3b;
    const void* rb[4]; const void* rpsi[4]; const void* rphi[4]; const void* rwr[4];
    const void* d1b; const void* dbng; const void* dbnb;
    const void* d2b; const void* bcb; const void* bgb;
    void* out;
    unsigned* bar;
    float* wpf; ushort_t* whi; ushort_t* wlo; float* dd;
    ushort_t* Thi; ushort_t* Tlo; float* Tp; ushort_t* A; ushort_t* UT;
};

// ---------------- phase: fused linear + BN(channel=n) + ReLU ---------------
// 2 active waves per block (one n each): n = blk*2 + w, all 512 blocks busy.
template<int K, int O, bool EXTIN, bool XF32>
__device__ void bnlin_dev(unsigned char* smem, const void* xin, const float* Wt,
    const void* bias, const void* bng, const void* bnb, ushort_t* out, int f32)
{
    constexpr int BR  = O/16;
    constexpr int NBT = 32/BR;
    constexpr int G   = K/8;
    constexpr int XSF = K*36;         // fp32 xst stride (elems per wave)
    constexpr int XSU = K*40;         // bf16 xst stride
    float* wt = (float*)smem;         // K*O fp32
    int t = threadIdx.x;
    int w = t >> 6, lane = t & 63;
    int n = blockIdx.x*2 + (w & 1);
    bool act = (w < 2);

    for (int i = t; i < K*O/4; i += TPB)
        ((float4*)wt)[i] = ((const float4*)Wt)[i];

    if (act){
        if (XF32){
            float* xst = (float*)(smem + (size_t)K*O*4) + w*XSF;
            for (int i = lane; i < 32*G; i += 64){
                int b = i / G, g = i - b*G;
                float f[8];
                if (EXTIN && f32){
                    const float* src = (const float*)xin + ((size_t)b*NN + n)*K + g*8;
                    float4 v0 = ((const float4*)src)[0];
                    float4 v1 = ((const float4*)src)[1];
                    f[0]=v0.x; f[1]=v0.y; f[2]=v0.z; f[3]=v0.w;
                    f[4]=v1.x; f[5]=v1.y; f[6]=v1.z; f[7]=v1.w;
                } else {
                    uint4 v = *(const uint4*)((const ushort_t*)xin + ((size_t)b*NN + n)*K + (size_t)g*8);
                    unpack8(v, f);
                }
                #pragma unroll
                for (int j=0;j<8;j++) xst[(g*8+j)*36 + b] = f[j];
            }
        } else {
            ushort_t* xst = (ushort_t*)(smem + (size_t)K*O*4) + w*XSU;
            for (int i = lane; i < 32*G; i += 64){
                int b = i / G, g = i - b*G;
                uint4 v = *(const uint4*)((const ushort_t*)xin + ((size_t)b*NN + n)*K + (size_t)g*8);
                xst[(g*8+0)*40 + b] = (ushort_t)(v.x & 0xffff);
                xst[(g*8+1)*40 + b] = (ushort_t)(v.x >> 16);
                xst[(g*8+2)*40 + b] = (ushort_t)(v.y & 0xffff);
                xst[(g*8+3)*40 + b] = (ushort_t)(v.y >> 16);
                xst[(g*8+4)*40 + b] = (ushort_t)(v.z & 0xffff);
                xst[(g*8+5)*40 + b] = (ushort_t)(v.z >> 16);
                xst[(g*8+6)*40 + b] = (ushort_t)(v.w & 0xffff);
                xst[(g*8+7)*40 + b] = (ushort_t)(v.w >> 16);
            }
        }
    }
    __syncthreads();
    if (!act) return;

    int bt = lane % NBT, jt = lane / NBT;
    int b0 = bt*BR, j0 = jt*8;
    float acc[BR][8];
    #pragma unroll
    for (int i=0;i<BR;i++)
        #pragma unroll
        for (int j=0;j<8;j++) acc[i][j] = 0.f;

    if (XF32){
        const float* xw = (const float*)(smem + (size_t)K*O*4) + w*XSF;
        for (int k = 0; k < K; k++){
            float xv[BR], wv[8];
            #pragma unroll
            for (int i=0;i<BR;i+=4)
                *(float4*)&xv[i] = *(const float4*)&xw[k*36 + b0 + i];
            *(float4*)&wv[0] = *(const float4*)&wt[k*O + j0];
            *(float4*)&wv[4] = *(const float4*)&wt[k*O + j0 + 4];
            #pragma unroll
            for (int i=0;i<BR;i++)
                #pragma unroll
                for (int j=0;j<8;j++) acc[i][j] = fmaf(xv[i], wv[j], acc[i][j]);
        }
    } else {
        const ushort_t* xw = (const ushort_t*)(smem + (size_t)K*O*4) + w*XSU;
        for (int k = 0; k < K; k++){
            float xv[8], wv[8];
            if (BR == 8){
                uint4 v = *(const uint4*)&xw[k*40 + b0];
                unpack8(v, xv);
            } else {
                uint2 v = *(const uint2*)&xw[k*40 + b0];
                unpack4(v, xv);
            }
            *(float4*)&wv[0] = *(const float4*)&wt[k*O + j0];
            *(float4*)&wv[4] = *(const float4*)&wt[k*O + j0 + 4];
            #pragma unroll
            for (int i=0;i<BR;i++)
                #pragma unroll
                for (int j=0;j<8;j++) acc[i][j] = fmaf(xv[i], wv[j], acc[i][j]);
        }
    }

    float bj[8];
    #pragma unroll
    for (int j=0;j<8;j++) bj[j] = ldin(bias, j0+j, f32);
    float s1 = 0.f, s2 = 0.f;
    #pragma unroll
    for (int i=0;i<BR;i++)
        #pragma unroll
        for (int j=0;j<8;j++){
            float a = acc[i][j] + bj[j];
            acc[i][j] = a; s1 += a; s2 = fmaf(a, a, s2);
        }
    #pragma unroll
    for (int off = 32; off > 0; off >>= 1){
        s1 += __shfl_down(s1, off);
        s2 += __shfl_down(s2, off);
    }
    s1 = __shfl(s1, 0); s2 = __shfl(s2, 0);
    const float M = 32.f * O;
    float m  = s1 / M;
    float vv = s2 / M - m*m;
    float rs = rsqrtf(vv + 1e-5f);
    float gv = ldin(bng, n, f32), bv = ldin(bnb, n, f32);
    #pragma unroll
    for (int i=0;i<BR;i++){
        union { uint4 u; ushort_t s[8]; } pk;
        #pragma unroll
        for (int j=0;j<8;j++)
            pk.s[j] = f2bf(fmaxf(fmaf(gv*(acc[i][j]-m), rs, bv), 0.f));
        *(uint4*)(out + ((size_t)(b0+i)*NN + n)*O + j0) = pk.u;
    }
}

// ---------------- phase: MFMA 128->128 linear (tile = blockIdx.x) ----------
template<int MODE>
__device__ void lin128_dev(unsigned char* smem, const ushort_t* xin,
    const ushort_t* Whi, const ushort_t* Wlo, const void* bias,
    ushort_t* outA, ushort_t* outUT, float* dvec, int f32)
{
    ushort_t* xs = (ushort_t*)smem;   // [k>>3][r(64)][8]  16 KB
    int t = threadIdx.x;
    size_t row0 = (size_t)blockIdx.x * 64;
    {
        const uint4* src = (const uint4*)(xin + row0*128);
        #pragma unroll
        for (int c = 0; c < 4; c++){
            int i = t + c*256;
            int r = i >> 4, kg = i & 15;
            *(uint4*)&xs[(kg*64 + r)*8] = src[i];
        }
    }
    __syncthreads();
    int w = t >> 6, lane = t & 63;
    int col = lane & 15, quad = lane >> 4;
    v4f acc[4][2];
    #pragma unroll
    for (int m=0;m<4;m++)
        #pragma unroll
        for (int nt=0;nt<2;nt++) acc[m][nt] = (v4f){0.f,0.f,0.f,0.f};

    #pragma unroll
    for (int kt = 0; kt < 4; kt++){
        int kg = kt*4 + quad;
        v8s a[4], bh[2], bl[2];
        #pragma unroll
        for (int nt=0;nt<2;nt++){
            int n = w*32 + nt*16 + col;
            bh[nt] = *(const v8s*)&Whi[(kg*128 + n)*8];
            bl[nt] = *(const v8s*)&Wlo[(kg*128 + n)*8];
        }
        #pragma unroll
        for (int m=0;m<4;m++)
            a[m] = *(const v8s*)&xs[(kg*64 + m*16 + col)*8];
        #pragma unroll
        for (int m=0;m<4;m++)
            #pragma unroll
            for (int nt=0;nt<2;nt++){
                acc[m][nt] = MFMA_BF16(a[m], bh[nt], acc[m][nt], 0, 0, 0);
                acc[m][nt] = MFMA_BF16(a[m], bl[nt], acc[m][nt], 0, 0, 0);
            }
    }
    int b = (int)(row0 >> 10);
    int rbase = (int)(row0 & 1023);
    #pragma unroll
    for (int nt=0;nt<2;nt++){
        int n = w*32 + nt*16 + col;
        float bn = ldin(bias, n, f32);
        #pragma unroll
        for (int m=0;m<4;m++){
            if (MODE == 0){
                #pragma unroll
                for (int reg=0;reg<4;reg++){
                    int r = m*16 + quad*4 + reg;
                    float v = acc[m][nt][reg] + bn;
                    outA[(row0 + r)*128 + n] = f2bf(1.f/(1.f+expf(-v)));
                }
            } else {
                union { uint2 u; ushort_t s[4]; } pk;
                #pragma unroll
                for (int reg=0;reg<4;reg++)
                    pk.s[reg] = f2bf(fmaxf(acc[m][nt][reg] + bn, 0.f));
                int rb = rbase + m*16 + quad*4;
                *(uint2*)&outUT[((size_t)b*128 + n)*1024 + rb] = pk.u;
            }
        }
    }
    if (MODE == 1 && t < 64){
        float s = 0.f;
        #pragma unroll 8
        for (int k=0;k<128;k++){
            float v = bf2f(xs[((k>>3)*64 + t)*8 + (k&7)]);
            s = fmaf(v, v, s);
        }
        dvec[row0 + t] = s;
    }
}

// ---------------- phase: Tt = U^T x, split-K x8, n split x2 (512 tiles) ----
__device__ void relT_dev(unsigned char* smem, const ushort_t* x,
    const ushort_t* UT, float* Tp)
{
    ushort_t* xts = (ushort_t*)smem;  // [r>>3][c][8]  16 KB
    int blk = blockIdx.x;
    int b = blk & 31, rs = (blk >> 5) & 7, nh = blk >> 8;   // nh in {0,1}
    int t = threadIdx.x;
    int w = t >> 6, lane = t & 63;
    int col = lane & 15, quad = lane >> 4;
    int wn = nh*64 + (w & 1)*32;      // 32-n slice per wave
    int wc = (w >> 1)*64;             // 64-c slice per wave
    const ushort_t* utb = UT + ((size_t)b << 17);
    v4f acc[2][4];
    #pragma unroll
    for (int m=0;m<2;m++)
        #pragma unroll
        for (int q=0;q<4;q++) acc[m][q] = (v4f){0.f,0.f,0.f,0.f};

    for (int ch = 0; ch < 2; ch++){
        __syncthreads();
        int r0 = rs*128 + ch*64;
        #pragma unroll
        for (int c = 0; c < 4; c++){           // x scatter-transpose
            int i = t + c*256;
            int r = i >> 4, cs8 = (i & 15)*8;
            uint4 v = *(const uint4*)&x[((size_t)b*1024 + r0 + r)*128 + cs8];
            int base = ((r >> 3)*128 + cs8)*8 + (r & 7);
            xts[base     ] = (ushort_t)(v.x & 0xffff);
            xts[base + 8 ] = (ushort_t)(v.x >> 16);
            xts[base + 16] = (ushort_t)(v.y & 0xffff);
            xts[base + 24] = (ushort_t)(v.y >> 16);
            xts[base + 32] = (ushort_t)(v.z & 0xffff);
            xts[base + 40] = (ushort_t)(v.z >> 16);
            xts[base + 48] = (ushort_t)(v.w & 0xffff);
            xts[base + 56] = (ushort_t)(v.w >> 16);
        }
        __syncthreads();
        #pragma unroll
        for (int kt = 0; kt < 2; kt++){
            int kg = kt*4 + quad;
            v8s a[2], bb[4];
            #pragma unroll
            for (int m=0;m<2;m++)
                a[m] = *(const v8s*)&utb[((size_t)(wn + m*16 + col))*1024 + r0 + kg*8];
            #pragma unroll
            for (int q=0;q<4;q++)
                bb[q] = *(const v8s*)&xts[(kg*128 + wc + q*16 + col)*8];
            #pragma unroll
            for (int m=0;m<2;m++)
                #pragma unroll
                for (int q=0;q<4;q++)
                    acc[m][q] = MFMA_BF16(a[m], bb[q], acc[m][q], 0, 0, 0);
        }
    }
    float* dst = Tp + (((size_t)rs*NB + b) << 14);
    #pragma unroll
    for (int m=0;m<2;m++)
        #pragma unroll
        for (int q=0;q<4;q++)
            #pragma unroll
            for (int reg=0;reg<4;reg++){
                int n = wn + m*16 + quad*4 + reg;
                int c = wc + q*16 + col;
                dst[n*128 + c] = acc[m][q][reg];
            }
}

// ---------------- phase: reduce partials -> Tt hi/lo (MFMA-B layout) -------
__device__ void tred_dev(const float* Tp, ushort_t* Thi, ushort_t* Tlo)
{
    const size_t S = 524288;
    for (int i = blockIdx.x*TPB + threadIdx.x; i < (int)S; i += NBLK*TPB){
        float s = ((Tp[i] + Tp[S+i]) + (Tp[2*S+i] + Tp[3*S+i]))
                + ((Tp[4*S+i] + Tp[5*S+i]) + (Tp[6*S+i] + Tp[7*S+i]));
        int bb = i >> 14, j = i & 16383;
        int n = j >> 7, c = j & 127;
        int di = (bb << 14) + ((c >> 3)*128 + n)*8 + (c & 7);
        ushort_t h = f2bf(s);
        Thi[di] = h;
        Tlo[di] = f2bf(s - bf2f(h));
    }
}

// ---------------- phase: relation output (in place, tile = blockIdx.x) -----
__device__ void relout_dev(unsigned char* smem, ushort_t* x, const ushort_t* UT,
    const ushort_t* Thi, const ushort_t* Tlo, const float* dvec,
    const void* psi, const void* phi, const void* wr, int f32)
{
    ushort_t* xs = (ushort_t*)smem;   // [c>>3][r(64)][8]  16 KB
    int t = threadIdx.x;
    size_t row0 = (size_t)blockIdx.x * 64;
    int b = (int)(row0 >> 10);
    int rbase = (int)(row0 & 1023);
    {
        const uint4* src = (const uint4*)(x + row0*128);
        #pragma unroll
        for (int c = 0; c < 4; c++){
            int i = t + c*256;
            int r = i >> 4, kg = i & 15;
            *(uint4*)&xs[(kg*64 + r)*8] = src[i];
        }
    }
    __syncthreads();
    float alpha = ldin(wr,0,f32) * ldin(psi,0,f32) * ldin(phi,0,f32) * (1.f/1024.f);
    int w = t >> 6, lane = t & 63;
    int col = lane & 15, quad = lane >> 4;
    const ushort_t* sh = Thi + ((size_t)b << 14);
    const ushort_t* sl = Tlo + ((size_t)b << 14);
    v4f acc[4][2];
    #pragma unroll
    for (int m=0;m<4;m++)
        #pragma unroll
        for (int nt=0;nt<2;nt++) acc[m][nt] = (v4f){0.f,0.f,0.f,0.f};

    #pragma unroll
    for (int kt = 0; kt < 4; kt++){
        int kg = kt*4 + quad;
        v8s a[4], bh[2], bl[2];
        #pragma unroll
        for (int nt=0;nt<2;nt++){
            int n = w*32 + nt*16 + col;
            bh[nt] = *(const v8s*)&sh[(kg*128 + n)*8];
            bl[nt] = *(const v8s*)&sl[(kg*128 + n)*8];
        }
        #pragma unroll
        for (int m=0;m<4;m++)
            a[m] = *(const v8s*)&xs[(kg*64 + m*16 + col)*8];
        #pragma unroll
        for (int m=0;m<4;m++)
            #pragma unroll
            for (int nt=0;nt<2;nt++){
                acc[m][nt] = MFMA_BF16(a[m], bh[nt], acc[m][nt], 0, 0, 0);
                acc[m][nt] = MFMA_BF16(a[m], bl[nt], acc[m][nt], 0, 0, 0);
            }
    }
    #pragma unroll
    for (int m=0;m<4;m++){
        float4 d4 = *(const float4*)&dvec[row0 + m*16 + quad*4];
        #pragma unroll
        for (int nt=0;nt<2;nt++){
            int n = w*32 + nt*16 + col;
            uint2 uu = *(const uint2*)&UT[((size_t)b*128 + n)*1024 + rbase + m*16 + quad*4];
            float uf[4];
            uf[0] = __uint_as_float(uu.x << 16);
            uf[1] = __uint_as_float(uu.x & 0xffff0000u);
            uf[2] = __uint_as_float(uu.y << 16);
            uf[3] = __uint_as_float(uu.y & 0xffff0000u);
            const float* dr = (const float*)&d4;
            #pragma unroll
            for (int reg=0;reg<4;reg++){
                int r = m*16 + quad*4 + reg;
                float xv = bf2f(xs[((n>>3)*64 + r)*8 + (n&7)]);
                float o = fmaf(alpha, acc[m][nt][reg] - dr[reg]*uf[reg], xv);
                x[(row0 + r)*128 + n] = f2bf(o);
            }
        }
    }
}

// ---------------- phase: decoder tail (8 tiles per block) ------------------
__device__ void dec2_dev(unsigned char* smem, const ushort_t* x,
    const float* W2t, const void* b2, const float* Wct, const void* bcb,
    const float* Wgt, const void* bgb, void* out, int f32)
{
    float* w2 = (float*)smem;            // 2048
    float* wc = w2 + 2048;               // 896
    float* wg = wc + 896;                // 128
    float* xs = wg + 128;                // 512
    float* hs = xs + 512;                // 264
    int t = threadIdx.x;
    for (int i=t;i<512;i+=TPB)  ((float4*)w2)[i] = ((const float4*)W2t)[i];
    if (t < 224) ((float4*)wc)[t] = ((const float4*)Wct)[t];
    if (t < 32)  ((float4*)wg)[t] = ((const float4*)Wgt)[t];
    int j = t & 31, r = t >> 5;
    for (int tile = blockIdx.x; tile < 4096; tile += NBLK){
        size_t row0 = (size_t)tile * 8;
        __syncthreads();
        if (t < 64){
            int row = t >> 3, seg = t & 7;
            uint4 v = *(const uint4*)&x[(row0 + row)*64 + seg*8];
            float f[8]; unpack8(v, f);
            *(float4*)&xs[row*64 + seg*8]     = make_float4(f[0],f[1],f[2],f[3]);
            *(float4*)&xs[row*64 + seg*8 + 4] = make_float4(f[4],f[5],f[6],f[7]);
        }
        __syncthreads();
        float a = ldin(b2, j, f32);
        #pragma unroll 8
        for (int k=0;k<64;k++) a = fmaf(xs[r*64 + k], w2[k*32 + j], a);
        hs[r*33 + j] = fmaxf(a, 0.f);
        __syncthreads();
        float o;
        if (j < 28){
            o = ldin(bcb, j, f32);
            #pragma unroll
            for (int k=0;k<32;k++) o = fmaf(hs[r*33 + k], wc[k*28 + j], o);
        } else {
            int jj = j - 28;
            o = ldin(bgb, jj, f32);
            #pragma unroll
            for (int k=0;k<32;k++) o = fmaf(hs[r*33 + k], wg[k*4 + jj], o);
        }
        size_t oi = (row0 + r)*32 + j;
        if (f32) ((float*)out)[oi] = o;
        else     ((ushort_t*)out)[oi] = f2bf(o);
    }
}

// ---------------- the mega-kernel ------------------------------------------
enum { O_E1=0, O_E2=2048, O_D1=10240, O_D2=18432, O_BC=20480, O_BG=21376 };

__global__ __launch_bounds__(TPB, 2) void k_mega(MegaArgs a)
{
    __shared__ __align__(16) unsigned char smem[53248];
    __shared__ int sflag;
    int t = threadIdx.x;

    if (t < 64){
        unsigned v = ((const unsigned*)a.input)[t];
        unsigned long long m = __ballot((v & 0x80008000u) != 0u);
        if (t == 0) sflag = (__popcll(m) > 4) ? 1 : 0;
    }
    __syncthreads();
    int f32 = sflag;

    // P1: weight prep
    {
        int gid = blockIdx.x*TPB + t;
        for (int s = 0; s < 6; s++){
            int O = a.pO[s], K = a.pK[s], sz = K*O;
            for (int i = gid; i < sz; i += NBLK*TPB){
                int k = i / O, j = i - k*O;
                a.wpf[a.poff[s] + i] = ldin(a.pw[s], (size_t)j*K + k, f32);
            }
        }
        for (int s = 6; s < 11; s++){
            for (int i = gid; i < 16384; i += NBLK*TPB){
                int n = i >> 7, k = i & 127;
                float v = ldin(a.pw[s], (size_t)n*128 + k, f32);
                ushort_t h = f2bf(v);
                ushort_t l = f2bf(v - bf2f(h));
                int di = (s - 6)*16384 + ((k >> 3)*128 + n)*8 + (k & 7);
                a.whi[di] = h; a.wlo[di] = l;
            }
        }
    }
    gbar(a.bar, 0);

    bnlin_dev<32,64,true,true>(smem, a.input, a.wpf+O_E1, a.e1b, a.bn1g, a.bn1b, a.A, f32);
    gbar(a.bar, 1);
    bnlin_dev<64,128,false,false>(smem, a.A, a.wpf+O_E2, a.e2b, a.bn2g, a.bn2b, a.UT, f32);
    gbar(a.bar, 2);
    lin128_dev<0>(smem, a.UT, a.whi, a.wlo, a.e3b, a.A, (ushort_t*)0, (float*)0, f32);
    gbar(a.bar, 3);

    int bi = 4;
    for (int r = 0; r < 4; r++){
        const ushort_t* wh = a.whi + (size_t)(1+r)*16384;
        const ushort_t* wl = a.wlo + (size_t)(1+r)*16384;
        lin128_dev<1>(smem, a.A, wh, wl, a.rb[r], (ushort_t*)0, a.UT, a.dd, f32);
        gbar(a.bar, bi++);
        relT_dev(smem, a.A, a.UT, a.Tp);
        gbar(a.bar, bi++);
        tred_dev(a.Tp, a.Thi, a.Tlo);
        gbar(a.bar, bi++);
        relout_dev(smem, a.A, a.UT, a.Thi, a.Tlo, a.dd,
                   a.rpsi[r], a.rphi[r], a.rwr[r], f32);
        gbar(a.bar, bi++);
    }

    bnlin_dev<128,64,false,false>(smem, a.A, a.wpf+O_D1, a.d1b, a.dbng, a.dbnb, a.UT, f32);
    gbar(a.bar, bi++);
    dec2_dev(smem, a.UT, a.wpf+O_D2, a.d2b, a.wpf+O_BC, a.bcb, a.wpf+O_BG, a.bgb, a.out, f32);
}

// ---------------------------------------------------------------------------
extern "C" void kernel_launch(void* const* d_in, const int* in_sizes, int n_in,
                              void* d_out, int out_size, void* d_ws, size_t ws_size,
                              hipStream_t stream)
{
    (void)in_sizes; (void)n_in; (void)out_size; (void)ws_size;
    MegaArgs a;
    a.input = d_in[0];
    const void* e1_W = d_in[1];  a.e1b = d_in[2];
    a.bn1g = d_in[3]; a.bn1b = d_in[4];
    const void* e2_W = d_in[5];  a.e2b = d_in[6];
    a.bn2g = d_in[7]; a.bn2b = d_in[8];
    const void* e3_W = d_in[9];  a.e3b = d_in[10];
    const void* rW[4];
    for (int r = 0; r < 4; r++){
        rW[r]     = d_in[11 + r*5 + 0];
        a.rb[r]   = d_in[11 + r*5 + 1];
        a.rpsi[r] = d_in[11 + r*5 + 2];
        a.rphi[r] = d_in[11 + r*5 + 3];
        a.rwr[r]  = d_in[11 + r*5 + 4];
    }
    const void* d1_W = d_in[31]; a.d1b = d_in[32];
    a.dbng = d_in[33]; a.dbnb = d_in[34];
    const void* d2_W = d_in[35]; a.d2b = d_in[36];
    const void* bc_W = d_in[37]; a.bcb = d_in[38];
    const void* bg_W = d_in[39]; a.bgb = d_in[40];
    a.out = d_out;

    // ---- workspace layout (36.2 MB), float offsets ----
    // bar   @ 0        (1024 f; only first 128 B used/zeroed)
    // wpf   @ 1024     (21504 f)
    // dd    @ 22528    (32768 f)
    // whi   @ 55296    (5*16384 us = 40960 f)
    // wlo   @ 96256    (40960 f)
    // Thi   @ 137216   (524288 us = 262144 f)
    // Tlo   @ 399360   (262144 f)
    // Tp    @ 661504   (4194304 f)
    // A     @ 4855808  ([32768][128] bf16 = 2097152 f)
    // UT    @ 6952960  ([32][128][1024] bf16 = 2097152 f)  ends @ 9050112 f
    float* ws_f = (float*)d_ws;
    a.bar = (unsigned*)d_ws;
    a.wpf = ws_f + 1024;
    a.dd  = ws_f + 22528;
    a.whi = (ushort_t*)(ws_f + 55296);
    a.wlo = (ushort_t*)(ws_f + 96256);
    a.Thi = (ushort_t*)(ws_f + 137216);
    a.Tlo = (ushort_t*)(ws_f + 399360);
    a.Tp  = ws_f + 661504;
    a.A   = (ushort_t*)(ws_f + 4855808);
    a.UT  = (ushort_t*)(ws_f + 6952960);

    const void* srcs[11] = {e1_W, e2_W, d1_W, d2_W, bc_W, bg_W,
                            e3_W, rW[0], rW[1], rW[2], rW[3]};
    const int  Ks[11]   = {32,64,128,64,32,32, 128,128,128,128,128};
    const int  Os[11]   = {64,128,64,32,28,4,  128,128,128,128,128};
    const int  offs[11] = {O_E1,O_E2,O_D1,O_D2,O_BC,O_BG, 0,0,0,0,0};
    for (int i=0;i<11;i++){ a.pw[i]=srcs[i]; a.pK[i]=Ks[i]; a.pO[i]=Os[i]; a.poff[i]=offs[i]; }

    hipMemsetAsync(d_ws, 0, 512, stream);         // zero the barrier arena
    k_mega<<<NBLK, TPB, 0, stream>>>(a);
}

// Round 9
// 346.324 us; speedup vs baseline: 4.9619x; 4.9619x over previous
//
#include <hip/hip_runtime.h>
#include <hip/hip_bf16.h>

// ---------------------------------------------------------------------------
// Generator_58737972740271.  R9: revert to R6 multi-kernel (mega-kernel's
// grid barriers cost ~60us each -> 1718us).  New: block-local fusion of
// relout_r + lin_{r+1} (both touch only the block's own 64 rows -> no global
// sync needed), lin<0>+lin<1> fused the same way, all outputs staged through
// LDS for coalesced uint4 stores, dtype-detect folded into each kernel.
// 21 -> 18 dispatches; A is never re-read between relout and lin.
// ---------------------------------------------------------------------------

typedef __hip_bfloat16 bf16;
typedef unsigned short ushort_t;
typedef float v4f __attribute__((ext_vector_type(4)));
typedef short v8s __attribute__((ext_vector_type(8)));
#define MFMA_BF16 __builtin_amdgcn_mfma_f32_16x16x32_bf16

#define NB 32
#define NN 1024

__device__ __forceinline__ float ldin(const void* p, size_t i, int f32){
    return f32 ? ((const float*)p)[i] : __bfloat162float(((const bf16*)p)[i]);
}
__device__ __forceinline__ float bf2f(ushort_t u){
    return __uint_as_float((unsigned)u << 16);
}
__device__ __forceinline__ ushort_t f2bf(float v){
    bf16 h = __float2bfloat16(v);
    ushort_t s; __builtin_memcpy(&s, &h, 2);
    return s;
}
__device__ __forceinline__ void unpack8(uint4 v, float* f){
    f[0] = __uint_as_float(v.x << 16);
    f[1] = __uint_as_float(v.x & 0xffff0000u);
    f[2] = __uint_as_float(v.y << 16);
    f[3] = __uint_as_float(v.y & 0xffff0000u);
    f[4] = __uint_as_float(v.z << 16);
    f[5] = __uint_as_float(v.z & 0xffff0000u);
    f[6] = __uint_as_float(v.w << 16);
    f[7] = __uint_as_float(v.w & 0xffff0000u);
}

// per-kernel dtype detect (input is uniform[0,1): fp32 words have random
// bit15; bf16 pairs have sign bits 15/31 == 0).
__device__ __forceinline__ int detect_dev(const void* inp){
    __shared__ int sflag;
    int t = threadIdx.x;
    if (t < 64){
        unsigned v = ((const unsigned*)inp)[t];
        unsigned long long m = __ballot((v & 0x80008000u) != 0u);
        if (t == 0) sflag = (__popcll(m) > 4) ? 1 : 0;
    }
    __syncthreads();
    return sflag;
}

// ---------------- prep: weights --------------------------------------------
// slabs 0..5: fp32 [K][O] (bnlin/dec2).  slabs 6..10: 128x128 -> hi/lo bf16
// in MFMA-B layout [k>>3][n][k&7]  (6=e3, 7..10=rW1..rW4).
struct PrepArgs {
    const void* w[11];
    int K[11], O[11], off[11];
};

__global__ __launch_bounds__(256) void k_prep(PrepArgs a, float* __restrict__ wpf,
                                              ushort_t* __restrict__ whi, ushort_t* __restrict__ wlo,
                                              const void* __restrict__ detin){
    int f32 = detect_dev(detin);
    int s = blockIdx.y;
    int idx = blockIdx.x*256 + threadIdx.x;
    if (s < 6){
        int K = a.K[s], O = a.O[s];
        if (idx >= K*O) return;
        int k = idx / O, j = idx - k*O;
        wpf[a.off[s] + idx] = ldin(a.w[s], (size_t)j*K + k, f32);
    } else {
        if (idx >= 16384) return;
        int n = idx >> 7, k = idx & 127;
        float v = ldin(a.w[s], (size_t)n*128 + k, f32);
        ushort_t h = f2bf(v);
        ushort_t l = f2bf(v - bf2f(h));
        int di = (s - 6)*16384 + ((k >> 3)*128 + n)*8 + (k & 7);
        whi[di] = h; wlo[di] = l;
    }
}

// ---------------- fused linear + BatchNorm(channel=n) + ReLU (VALU) --------
template<int K, int O, bool EXTIN>
__global__ __launch_bounds__(128) void k_bnlin(
    const void* __restrict__ xin, const float* __restrict__ Wt,
    const void* __restrict__ bias, const void* __restrict__ bng,
    const void* __restrict__ bnb, ushort_t* __restrict__ out,
    const void* __restrict__ detin)
{
    int f32 = detect_dev(detin);
    constexpr int BR  = O/16;
    constexpr int NBT = 32/BR;
    constexpr int G   = K/8;
    __shared__ __align__(16) float wt[K*O];
    __shared__ __align__(16) float xst[2][K*36];
    int t = threadIdx.x;
    int w = t >> 6, lane = t & 63;
    int n = blockIdx.x*2 + w;

    for (int i = t; i < K*O/4; i += 128)
        ((float4*)wt)[i] = ((const float4*)Wt)[i];
    for (int i = lane; i < 32*G; i += 64){
        int b = i / G, g = i - b*G;
        float f[8];
        if (EXTIN && f32){
            const float* src = (const float*)xin + ((size_t)b*NN + n)*K + g*8;
            float4 v0 = ((const float4*)src)[0];
            float4 v1 = ((const float4*)src)[1];
            f[0]=v0.x; f[1]=v0.y; f[2]=v0.z; f[3]=v0.w;
            f[4]=v1.x; f[5]=v1.y; f[6]=v1.z; f[7]=v1.w;
        } else {
            uint4 v = *(const uint4*)((const ushort_t*)xin + ((size_t)b*NN + n)*K + (size_t)g*8);
            unpack8(v, f);
        }
        #pragma unroll
        for (int j=0;j<8;j++) xst[w][(g*8+j)*36 + b] = f[j];
    }
    __syncthreads();

    int bt = lane % NBT, jt = lane / NBT;
    int b0 = bt*BR, j0 = jt*8;
    const float* xw = xst[w];
    float acc[BR][8];
    #pragma unroll
    for (int i=0;i<BR;i++)
        #pragma unroll
        for (int j=0;j<8;j++) acc[i][j] = 0.f;

    for (int k = 0; k < K; k++){
        float xv[BR], wv[8];
        #pragma unroll
        for (int i=0;i<BR;i+=4)
            *(float4*)&xv[i] = *(const float4*)&xw[k*36 + b0 + i];
        *(float4*)&wv[0] = *(const float4*)&wt[k*O + j0];
        *(float4*)&wv[4] = *(const float4*)&wt[k*O + j0 + 4];
        #pragma unroll
        for (int i=0;i<BR;i++)
            #pragma unroll
            for (int j=0;j<8;j++) acc[i][j] = fmaf(xv[i], wv[j], acc[i][j]);
    }

    float bj[8];
    #pragma unroll
    for (int j=0;j<8;j++) bj[j] = ldin(bias, j0+j, f32);
    float s1 = 0.f, s2 = 0.f;
    #pragma unroll
    for (int i=0;i<BR;i++)
        #pragma unroll
        for (int j=0;j<8;j++){
            float a = acc[i][j] + bj[j];
            acc[i][j] = a; s1 += a; s2 = fmaf(a, a, s2);
        }
    #pragma unroll
    for (int off = 32; off > 0; off >>= 1){
        s1 += __shfl_down(s1, off);
        s2 += __shfl_down(s2, off);
    }
    s1 = __shfl(s1, 0); s2 = __shfl(s2, 0);
    const float M = 32.f * O;
    float m  = s1 / M;
    float vv = s2 / M - m*m;
    float rs = rsqrtf(vv + 1e-5f);
    float gv = ldin(bng, n, f32), bv = ldin(bnb, n, f32);
    #pragma unroll
    for (int i=0;i<BR;i++){
        union { uint4 u; ushort_t s[8]; } pk;
        #pragma unroll
        for (int j=0;j<8;j++)
            pk.s[j] = f2bf(fmaxf(fmaf(gv*(acc[i][j]-m), rs, bv), 0.f));
        *(uint4*)(out + ((size_t)(b0+i)*NN + n)*O + j0) = pk.u;
    }
}

// ---------------- shared tails for the fused MFMA kernels ------------------
// After the producing stage leaves x' (bf16 in o[] regs), these write x' to
// LDS (A-layout), to global A (coalesced), compute dvec, run the next linear
// (relu) and write UT (coalesced).  Block owns rows [row0,row0+64).

// x'/u value owner mapping: lane has (r = m*16+quad*4+reg, n = w*32+nt*16+col).

__device__ __forceinline__ void tail_stage_x(ushort_t* xs, const float o[2][16],
                                             int w, int col, int quad){
    #pragma unroll
    for (int nt=0;nt<2;nt++){
        int n = w*32 + nt*16 + col;
        #pragma unroll
        for (int m=0;m<4;m++)
            #pragma unroll
            for (int reg=0;reg<4;reg++){
                int r = m*16 + quad*4 + reg;
                xs[((n>>3)*64 + r)*8 + (n&7)] = f2bf(o[nt][m*4+reg]);
            }
    }
}

__device__ __forceinline__ void tail_write_A(const ushort_t* xs, ushort_t* A,
                                             size_t row0, int t){
    uint4* dst = (uint4*)(A + row0*128);
    #pragma unroll
    for (int c = 0; c < 4; c++){
        int i = t + c*256;
        int r = i >> 4, kg = i & 15;
        dst[i] = *(const uint4*)&xs[(kg*64 + r)*8];
    }
}

// next linear: U = relu(x'·W^T + b), staged to xs as [n][64 r], then coalesced.
__device__ __forceinline__ void tail_lin_relu(ushort_t* xs, ushort_t* UT,
    const ushort_t* Whi, const ushort_t* Wlo, const void* bias, float* dvec,
    size_t row0, int b, int rbase, int t, int w, int lane, int col, int quad, int f32)
{
    if (t < 64){
        float s = 0.f;
        #pragma unroll 8
        for (int k=0;k<128;k++){
            float v = bf2f(xs[((k>>3)*64 + t)*8 + (k&7)]);
            s = fmaf(v, v, s);
        }
        dvec[row0 + t] = s;
    }
    v4f acc[4][2];
    #pragma unroll
    for (int m=0;m<4;m++)
        #pragma unroll
        for (int nt=0;nt<2;nt++) acc[m][nt] = (v4f){0.f,0.f,0.f,0.f};
    #pragma unroll
    for (int kt = 0; kt < 4; kt++){
        int kg = kt*4 + quad;
        v8s a[4], bh[2], bl[2];
        #pragma unroll
        for (int nt=0;nt<2;nt++){
            int n = w*32 + nt*16 + col;
            bh[nt] = *(const v8s*)&Whi[(kg*128 + n)*8];
            bl[nt] = *(const v8s*)&Wlo[(kg*128 + n)*8];
        }
        #pragma unroll
        for (int m=0;m<4;m++)
            a[m] = *(const v8s*)&xs[(kg*64 + m*16 + col)*8];
        #pragma unroll
        for (int m=0;m<4;m++)
            #pragma unroll
            for (int nt=0;nt<2;nt++){
                acc[m][nt] = MFMA_BF16(a[m], bh[nt], acc[m][nt], 0, 0, 0);
                acc[m][nt] = MFMA_BF16(a[m], bl[nt], acc[m][nt], 0, 0, 0);
            }
    }
    float u[2][16];
    #pragma unroll
    for (int nt=0;nt<2;nt++){
        int n = w*32 + nt*16 + col;
        float bn = ldin(bias, n, f32);
        #pragma unroll
        for (int m=0;m<4;m++)
            #pragma unroll
            for (int reg=0;reg<4;reg++)
                u[nt][m*4+reg] = fmaxf(acc[m][nt][reg] + bn, 0.f);
    }
    __syncthreads();           // xs reads (a-frags, dvec) done
    #pragma unroll
    for (int nt=0;nt<2;nt++){
        int n = w*32 + nt*16 + col;
        #pragma unroll
        for (int m=0;m<4;m++)
            #pragma unroll
            for (int reg=0;reg<4;reg++){
                int r = m*16 + quad*4 + reg;
                xs[n*64 + r] = f2bf(u[nt][m*4+reg]);
            }
    }
    __syncthreads();
    #pragma unroll
    for (int c = 0; c < 4; c++){
        int i = t + c*256;
        int n = i >> 3, sg = i & 7;
        *(uint4*)&UT[((size_t)b*128 + n)*1024 + rbase + sg*8] =
            *(const uint4*)&xs[n*64 + sg*8];
    }
}

// ---------------- fused: enc3 sigmoid + relation-1 U -----------------------
__global__ __launch_bounds__(256, 2) void k_linfuse0(
    const ushort_t* __restrict__ xin,                 // E2, row-major
    const ushort_t* __restrict__ W3h, const ushort_t* __restrict__ W3l,
    const void* __restrict__ b3,
    const ushort_t* __restrict__ W1h, const ushort_t* __restrict__ W1l,
    const void* __restrict__ b1,
    ushort_t* __restrict__ A, ushort_t* __restrict__ UT,
    float* __restrict__ dvec, const void* __restrict__ detin)
{
    __shared__ __align__(16) ushort_t xs[8192];
    int f32 = detect_dev(detin);
    int t = threadIdx.x;
    size_t row0 = (size_t)blockIdx.x * 64;
    int b = (int)(row0 >> 10), rbase = (int)(row0 & 1023);
    {
        const uint4* src = (const uint4*)(xin + row0*128);
        #pragma unroll
        for (int c = 0; c < 4; c++){
            int i = t + c*256;
            int r = i >> 4, kg = i & 15;
            *(uint4*)&xs[(kg*64 + r)*8] = src[i];
        }
    }
    __syncthreads();
    int w = t >> 6, lane = t & 63;
    int col = lane & 15, quad = lane >> 4;
    v4f acc[4][2];
    #pragma unroll
    for (int m=0;m<4;m++)
        #pragma unroll
        for (int nt=0;nt<2;nt++) acc[m][nt] = (v4f){0.f,0.f,0.f,0.f};
    #pragma unroll
    for (int kt = 0; kt < 4; kt++){
        int kg = kt*4 + quad;
        v8s a[4], bh[2], bl[2];
        #pragma unroll
        for (int nt=0;nt<2;nt++){
            int n = w*32 + nt*16 + col;
            bh[nt] = *(const v8s*)&W3h[(kg*128 + n)*8];
            bl[nt] = *(const v8s*)&W3l[(kg*128 + n)*8];
        }
        #pragma unroll
        for (int m=0;m<4;m++)
            a[m] = *(const v8s*)&xs[(kg*64 + m*16 + col)*8];
        #pragma unroll
        for (int m=0;m<4;m++)
            #pragma unroll
            for (int nt=0;nt<2;nt++){
                acc[m][nt] = MFMA_BF16(a[m], bh[nt], acc[m][nt], 0, 0, 0);
                acc[m][nt] = MFMA_BF16(a[m], bl[nt], acc[m][nt], 0, 0, 0);
            }
    }
    float o[2][16];
    #pragma unroll
    for (int nt=0;nt<2;nt++){
        int n = w*32 + nt*16 + col;
        float bn = ldin(b3, n, f32);
        #pragma unroll
        for (int m=0;m<4;m++)
            #pragma unroll
            for (int reg=0;reg<4;reg++){
                float v = acc[m][nt][reg] + bn;
                o[nt][m*4+reg] = 1.f/(1.f+expf(-v));
            }
    }
    __syncthreads();
    tail_stage_x(xs, o, w, col, quad);
    __syncthreads();
    tail_write_A(xs, A, row0, t);
    tail_lin_relu(xs, UT, W1h, W1l, b1, dvec, row0, b, rbase, t, w, lane, col, quad, f32);
}

// ---------------- relT: Tt = U^T x, split-K x8, n-half x2 (512 blocks) -----
__global__ __launch_bounds__(256) void k_relT(
    const ushort_t* __restrict__ x, const ushort_t* __restrict__ UT,
    float* __restrict__ Tp)
{
    __shared__ __align__(16) ushort_t xts[8192];
    int blk = blockIdx.x;
    int b = blk & 31, rs = (blk >> 5) & 7, nh = blk >> 8;
    int t = threadIdx.x;
    int w = t >> 6, lane = t & 63;
    int col = lane & 15, quad = lane >> 4;
    int wn = nh*64 + (w & 1)*32;
    int wc = (w >> 1)*64;
    const ushort_t* utb = UT + ((size_t)b << 17);
    v4f acc[2][4];
    #pragma unroll
    for (int m=0;m<2;m++)
        #pragma unroll
        for (int q=0;q<4;q++) acc[m][q] = (v4f){0.f,0.f,0.f,0.f};

    for (int ch = 0; ch < 2; ch++){
        __syncthreads();
        int r0 = rs*128 + ch*64;
        #pragma unroll
        for (int c = 0; c < 4; c++){
            int i = t + c*256;
            int r = i >> 4, cs8 = (i & 15)*8;
            uint4 v = *(const uint4*)&x[((size_t)b*1024 + r0 + r)*128 + cs8];
            int base = ((r >> 3)*128 + cs8)*8 + (r & 7);
            xts[base     ] = (ushort_t)(v.x & 0xffff);
            xts[base + 8 ] = (ushort_t)(v.x >> 16);
            xts[base + 16] = (ushort_t)(v.y & 0xffff);
            xts[base + 24] = (ushort_t)(v.y >> 16);
            xts[base + 32] = (ushort_t)(v.z & 0xffff);
            xts[base + 40] = (ushort_t)(v.z >> 16);
            xts[base + 48] = (ushort_t)(v.w & 0xffff);
            xts[base + 56] = (ushort_t)(v.w >> 16);
        }
        __syncthreads();
        #pragma unroll
        for (int kt = 0; kt < 2; kt++){
            int kg = kt*4 + quad;
            v8s a[2], bb[4];
            #pragma unroll
            for (int m=0;m<2;m++)
                a[m] = *(const v8s*)&utb[((size_t)(wn + m*16 + col))*1024 + r0 + kg*8];
            #pragma unroll
            for (int q=0;q<4;q++)
                bb[q] = *(const v8s*)&xts[(kg*128 + wc + q*16 + col)*8];
            #pragma unroll
            for (int m=0;m<2;m++)
                #pragma unroll
                for (int q=0;q<4;q++)
                    acc[m][q] = MFMA_BF16(a[m], bb[q], acc[m][q], 0, 0, 0);
        }
    }
    float* dst = Tp + (((size_t)rs*NB + b) << 14);
    #pragma unroll
    for (int m=0;m<2;m++)
        #pragma unroll
        for (int q=0;q<4;q++)
            #pragma unroll
            for (int reg=0;reg<4;reg++){
                int n = wn + m*16 + quad*4 + reg;
                int c = wc + q*16 + col;
                dst[n*128 + c] = acc[m][q][reg];
            }
}

// ---------------- reduce partials -> Tt hi/lo (MFMA-B layout) --------------
__global__ __launch_bounds__(256) void k_tred(const float* __restrict__ Tp,
                                              ushort_t* __restrict__ Thi, ushort_t* __restrict__ Tlo){
    int i = blockIdx.x*256 + threadIdx.x;
    const size_t S = 524288;
    float s = ((Tp[i] + Tp[S+i]) + (Tp[2*S+i] + Tp[3*S+i]))
            + ((Tp[4*S+i] + Tp[5*S+i]) + (Tp[6*S+i] + Tp[7*S+i]));
    int bb = i >> 14, j = i & 16383;
    int n = j >> 7, c = j & 127;
    int di = (bb << 14) + ((c >> 3)*128 + n)*8 + (c & 7);
    ushort_t h = f2bf(s);
    Thi[di] = h;
    Tlo[di] = f2bf(s - bf2f(h));
}

// ---------------- fused: relout_r (+ lin_{r+1} unless LAST) ----------------
template<int LAST>
__global__ __launch_bounds__(256, 2) void k_relfuse(
    ushort_t* __restrict__ x, ushort_t* __restrict__ UT,
    const ushort_t* __restrict__ Thi, const ushort_t* __restrict__ Tlo,
    float* __restrict__ dvec,
    const void* __restrict__ psi, const void* __restrict__ phi, const void* __restrict__ wr,
    const ushort_t* __restrict__ Wnh, const ushort_t* __restrict__ Wnl,
    const void* __restrict__ bnext, const void* __restrict__ detin)
{
    __shared__ __align__(16) ushort_t xs[8192];
    int f32 = detect_dev(detin);
    int t = threadIdx.x;
    size_t row0 = (size_t)blockIdx.x * 64;
    int b = (int)(row0 >> 10), rbase = (int)(row0 & 1023);
    {
        const uint4* src = (const uint4*)(x + row0*128);
        #pragma unroll
        for (int c = 0; c < 4; c++){
            int i = t + c*256;
            int r = i >> 4, kg = i & 15;
            *(uint4*)&xs[(kg*64 + r)*8] = src[i];
        }
    }
    __syncthreads();
    float alpha = ldin(wr,0,f32) * ldin(psi,0,f32) * ldin(phi,0,f32) * (1.f/1024.f);
    int w = t >> 6, lane = t & 63;
    int col = lane & 15, quad = lane >> 4;
    const ushort_t* sh = Thi + ((size_t)b << 14);
    const ushort_t* sl = Tlo + ((size_t)b << 14);
    v4f acc[4][2];
    #pragma unroll
    for (int m=0;m<4;m++)
        #pragma unroll
        for (int nt=0;nt<2;nt++) acc[m][nt] = (v4f){0.f,0.f,0.f,0.f};
    #pragma unroll
    for (int kt = 0; kt < 4; kt++){
        int kg = kt*4 + quad;
        v8s a[4], bh[2], bl[2];
        #pragma unroll
        for (int nt=0;nt<2;nt++){
            int n = w*32 + nt*16 + col;
            bh[nt] = *(const v8s*)&sh[(kg*128 + n)*8];
            bl[nt] = *(const v8s*)&sl[(kg*128 + n)*8];
        }
        #pragma unroll
        for (int m=0;m<4;m++)
            a[m] = *(const v8s*)&xs[(kg*64 + m*16 + col)*8];
        #pragma unroll
        for (int m=0;m<4;m++)
            #pragma unroll
            for (int nt=0;nt<2;nt++){
                acc[m][nt] = MFMA_BF16(a[m], bh[nt], acc[m][nt], 0, 0, 0);
                acc[m][nt] = MFMA_BF16(a[m], bl[nt], acc[m][nt], 0, 0, 0);
            }
    }
    float o[2][16];
    #pragma unroll
    for (int m=0;m<4;m++){
        float4 d4 = *(const float4*)&dvec[row0 + m*16 + quad*4];
        const float* dr = (const float*)&d4;
        #pragma unroll
        for (int nt=0;nt<2;nt++){
            int n = w*32 + nt*16 + col;
            uint2 uu = *(const uint2*)&UT[((size_t)b*128 + n)*1024 + rbase + m*16 + quad*4];
            float uf[4];
            uf[0] = __uint_as_float(uu.x << 16);
            uf[1] = __uint_as_float(uu.x & 0xffff0000u);
            uf[2] = __uint_as_float(uu.y << 16);
            uf[3] = __uint_as_float(uu.y & 0xffff0000u);
            #pragma unroll
            for (int reg=0;reg<4;reg++){
                int r = m*16 + quad*4 + reg;
                float xv = bf2f(xs[((n>>3)*64 + r)*8 + (n&7)]);
                o[nt][m*4+reg] = fmaf(alpha, acc[m][nt][reg] - dr[reg]*uf[reg], xv);
            }
        }
    }
    __syncthreads();           // all xs / dvec / UT reads done
    tail_stage_x(xs, o, w, col, quad);
    __syncthreads();
    tail_write_A(xs, x, row0, t);
    if (!LAST)
        tail_lin_relu(xs, UT, Wnh, Wnl, bnext, dvec, row0, b, rbase, t, w, lane, col, quad, f32);
}

// ---------------- decoder tail ---------------------------------------------
__global__ __launch_bounds__(256) void k_dec2(
    const ushort_t* __restrict__ x,       // [B,N,64]
    const float* __restrict__ W2t, const void* __restrict__ b2,
    const float* __restrict__ Wct, const void* __restrict__ bcb,
    const float* __restrict__ Wgt, const void* __restrict__ bgb,
    void* __restrict__ out, const void* __restrict__ detin)
{
    int f32 = detect_dev(detin);
    __shared__ __align__(16) float w2[64*32];
    __shared__ __align__(16) float wc[32*28];
    __shared__ __align__(16) float wg[32*4];
    __shared__ __align__(16) float xsd[8][64];
    __shared__ float hs[8][33];
    size_t row0 = (size_t)blockIdx.x * 8;
    int t = threadIdx.x;
    for (int i=t;i<512;i+=256)  ((float4*)w2)[i] = ((const float4*)W2t)[i];
    if (t < 224) ((float4*)wc)[t] = ((const float4*)Wct)[t];
    if (t < 32)  ((float4*)wg)[t] = ((const float4*)Wgt)[t];
    if (t < 64){
        int row = t >> 3, seg = t & 7;
        uint4 v = *(const uint4*)&x[(row0 + row)*64 + seg*8];
        float f[8]; unpack8(v, f);
        *(float4*)&xsd[row][seg*8]   = make_float4(f[0],f[1],f[2],f[3]);
        *(float4*)&xsd[row][seg*8+4] = make_float4(f[4],f[5],f[6],f[7]);
    }
    __syncthreads();
    int j = t & 31, r = t >> 5;
    float a = ldin(b2, j, f32);
    #pragma unroll 8
    for (int k=0;k<64;k++) a = fmaf(xsd[r][k], w2[k*32 + j], a);
    hs[r][j] = fmaxf(a, 0.f);
    __syncthreads();
    float o;
    if (j < 28){
        o = ldin(bcb, j, f32);
        #pragma unroll
        for (int k=0;k<32;k++) o = fmaf(hs[r][k], wc[k*28 + j], o);
    } else {
        int jj = j - 28;
        o = ldin(bgb, jj, f32);
        #pragma unroll
        for (int k=0;k<32;k++) o = fmaf(hs[r][k], wg[k*4 + jj], o);
    }
    size_t oi = (row0 + r)*32 + j;
    if (f32) ((float*)out)[oi] = o;
    else     ((ushort_t*)out)[oi] = f2bf(o);
}

// ---------------------------------------------------------------------------
enum { O_E1=0, O_E2=2048, O_D1=10240, O_D2=18432, O_BC=20480, O_BG=21376 };

extern "C" void kernel_launch(void* const* d_in, const int* in_sizes, int n_in,
                              void* d_out, int out_size, void* d_ws, size_t ws_size,
                              hipStream_t stream)
{
    (void)in_sizes; (void)n_in; (void)out_size; (void)ws_size;
    const void* input = d_in[0];
    const void* e1_W = d_in[1];  const void* e1_b = d_in[2];
    const void* bn1_g = d_in[3]; const void* bn1_b = d_in[4];
    const void* e2_W = d_in[5];  const void* e2_b = d_in[6];
    const void* bn2_g = d_in[7]; const void* bn2_b = d_in[8];
    const void* e3_W = d_in[9];  const void* e3_b = d_in[10];
    const void *rW[4], *rb[4], *rpsi[4], *rphi[4], *rwr[4];
    for (int r = 0; r < 4; r++){
        rW[r]   = d_in[11 + r*5 + 0];
        rb[r]   = d_in[11 + r*5 + 1];
        rpsi[r] = d_in[11 + r*5 + 2];
        rphi[r] = d_in[11 + r*5 + 3];
        rwr[r]  = d_in[11 + r*5 + 4];
    }
    const void* d1_W = d_in[31]; const void* d1_b = d_in[32];
    const void* dbn_g = d_in[33];const void* dbn_b = d_in[34];
    const void* d2_W = d_in[35]; const void* d2_b = d_in[36];
    const void* bc_W = d_in[37]; const void* bc_b = d_in[38];
    const void* bg_W = d_in[39]; const void* bg_b = d_in[40];

    // ---- workspace layout (36.2 MB), float offsets (all 16B-aligned) ----
    float*    ws_f = (float*)d_ws;
    float*    wpf  = ws_f;                         // 21504 f
    float*    dd   = ws_f + 21504;                 // 32768 f
    ushort_t* whi  = (ushort_t*)(ws_f + 54272);    // 5*16384 us
    ushort_t* wlo  = (ushort_t*)(ws_f + 95232);    // 5*16384 us
    ushort_t* Thi  = (ushort_t*)(ws_f + 136192);   // 524288 us
    ushort_t* Tlo  = (ushort_t*)(ws_f + 398336);   // 524288 us
    float*    Tp   = ws_f + 660480;                // 4194304 f
    ushort_t* A    = (ushort_t*)(ws_f + 4854784);  // [32768][128] bf16
    ushort_t* UT   = (ushort_t*)(ws_f + 6951936);  // [32][128][1024] bf16
    ushort_t* Cenc = A;                            // [32768][64] overlays A
    ushort_t* E2   = (ushort_t*)Tp;                // [32768][128] overlays Tp
    ushort_t* Cdec = UT;                           // [32768][64] overlays UT

    PrepArgs pa;
    const void* srcs[11] = {e1_W, e2_W, d1_W, d2_W, bc_W, bg_W,
                            e3_W, rW[0], rW[1], rW[2], rW[3]};
    const int  Ks[11]   = {32,64,128,64,32,32, 128,128,128,128,128};
    const int  Os[11]   = {64,128,64,32,28,4,  128,128,128,128,128};
    const int  offs[11] = {O_E1,O_E2,O_D1,O_D2,O_BC,O_BG, 0,0,0,0,0};
    for (int i=0;i<11;i++){ pa.w[i]=srcs[i]; pa.K[i]=Ks[i]; pa.O[i]=Os[i]; pa.off[i]=offs[i]; }

    k_prep<<<dim3(64,11), 256, 0, stream>>>(pa, wpf, whi, wlo, input);
    k_bnlin<32,64,true><<<512, 128, 0, stream>>>(input, wpf+O_E1, e1_b, bn1_g, bn1_b, Cenc, input);
    k_bnlin<64,128,false><<<512, 128, 0, stream>>>(Cenc, wpf+O_E2, e2_b, bn2_g, bn2_b, E2, input);
    k_linfuse0<<<512, 256, 0, stream>>>(E2, whi, wlo, e3_b,
                                        whi + 16384, wlo + 16384, rb[0],
                                        A, UT, dd, input);

    for (int r = 0; r < 4; r++){
        k_relT<<<512, 256, 0, stream>>>(A, UT, Tp);
        k_tred<<<2048, 256, 0, stream>>>(Tp, Thi, Tlo);
        if (r < 3)
            k_relfuse<0><<<512, 256, 0, stream>>>(A, UT, Thi, Tlo, dd,
                rpsi[r], rphi[r], rwr[r],
                whi + (size_t)(2+r)*16384, wlo + (size_t)(2+r)*16384, rb[r+1], input);
        else
            k_relfuse<1><<<512, 256, 0, stream>>>(A, UT, Thi, Tlo, dd,
                rpsi[r], rphi[r], rwr[r], whi, wlo, rb[r], input);
    }

    k_bnlin<128,64,false><<<512, 128, 0, stream>>>(A, wpf+O_D1, d1_b, dbn_g, dbn_b, Cdec, input);
    k_dec2<<<4096, 256, 0, stream>>>(Cdec, wpf+O_D2, d2_b, wpf+O_BC, bc_b, wpf+O_BG, bg_b, d_out, input);
}

// Round 10
// 326.371 us; speedup vs baseline: 5.2653x; 1.0611x over previous
//
#include <hip/hip_runtime.h>
#include <hip/hip_bf16.h>

// ---------------------------------------------------------------------------
// Generator_58737972740271.  R10: eliminate k_relT entirely — each fused
// lin/relout block emits its own 64-row T-partial (Tp[s][b] = U_rows^T x_rows)
// from operands already staged in LDS (x' -> xt [c][64r], u -> xs [n][64r]).
// k_tred sums 16 partials (was 8).  18 -> 14 dispatches; no global x/UT
// re-read for T; packed uint2 LDS staging.  Numerics unchanged (fp32 partials,
// bf16 operands at the same rounding points).
// ---------------------------------------------------------------------------

typedef __hip_bfloat16 bf16;
typedef unsigned short ushort_t;
typedef float v4f __attribute__((ext_vector_type(4)));
typedef short v8s __attribute__((ext_vector_type(8)));
#define MFMA_BF16 __builtin_amdgcn_mfma_f32_16x16x32_bf16

#define NB 32
#define NN 1024

__device__ __forceinline__ float ldin(const void* p, size_t i, int f32){
    return f32 ? ((const float*)p)[i] : __bfloat162float(((const bf16*)p)[i]);
}
__device__ __forceinline__ float bf2f(ushort_t u){
    return __uint_as_float((unsigned)u << 16);
}
__device__ __forceinline__ ushort_t f2bf(float v){
    bf16 h = __float2bfloat16(v);
    ushort_t s; __builtin_memcpy(&s, &h, 2);
    return s;
}
__device__ __forceinline__ void unpack8(uint4 v, float* f){
    f[0] = __uint_as_float(v.x << 16);
    f[1] = __uint_as_float(v.x & 0xffff0000u);
    f[2] = __uint_as_float(v.y << 16);
    f[3] = __uint_as_float(v.y & 0xffff0000u);
    f[4] = __uint_as_float(v.z << 16);
    f[5] = __uint_as_float(v.z & 0xffff0000u);
    f[6] = __uint_as_float(v.w << 16);
    f[7] = __uint_as_float(v.w & 0xffff0000u);
}

// per-kernel dtype detect (input is uniform[0,1): fp32 words have random
// bit15; bf16 pairs have sign bits 15/31 == 0).
__device__ __forceinline__ int detect_dev(const void* inp){
    __shared__ int sflag;
    int t = threadIdx.x;
    if (t < 64){
        unsigned v = ((const unsigned*)inp)[t];
        unsigned long long m = __ballot((v & 0x80008000u) != 0u);
        if (t == 0) sflag = (__popcll(m) > 4) ? 1 : 0;
    }
    __syncthreads();
    return sflag;
}

// ---------------- prep: weights --------------------------------------------
struct PrepArgs {
    const void* w[11];
    int K[11], O[11], off[11];
};

__global__ __launch_bounds__(256) void k_prep(PrepArgs a, float* __restrict__ wpf,
                                              ushort_t* __restrict__ whi, ushort_t* __restrict__ wlo,
                                              const void* __restrict__ detin){
    int f32 = detect_dev(detin);
    int s = blockIdx.y;
    int idx = blockIdx.x*256 + threadIdx.x;
    if (s < 6){
        int K = a.K[s], O = a.O[s];
        if (idx >= K*O) return;
        int k = idx / O, j = idx - k*O;
        wpf[a.off[s] + idx] = ldin(a.w[s], (size_t)j*K + k, f32);
    } else {
        if (idx >= 16384) return;
        int n = idx >> 7, k = idx & 127;
        float v = ldin(a.w[s], (size_t)n*128 + k, f32);
        ushort_t h = f2bf(v);
        ushort_t l = f2bf(v - bf2f(h));
        int di = (s - 6)*16384 + ((k >> 3)*128 + n)*8 + (k & 7);
        whi[di] = h; wlo[di] = l;
    }
}

// ---------------- fused linear + BatchNorm(channel=n) + ReLU (VALU) --------
template<int K, int O, bool EXTIN>
__global__ __launch_bounds__(128) void k_bnlin(
    const void* __restrict__ xin, const float* __restrict__ Wt,
    const void* __restrict__ bias, const void* __restrict__ bng,
    const void* __restrict__ bnb, ushort_t* __restrict__ out,
    const void* __restrict__ detin)
{
    int f32 = detect_dev(detin);
    constexpr int BR  = O/16;
    constexpr int NBT = 32/BR;
    constexpr int G   = K/8;
    __shared__ __align__(16) float wt[K*O];
    __shared__ __align__(16) float xst[2][K*36];
    int t = threadIdx.x;
    int w = t >> 6, lane = t & 63;
    int n = blockIdx.x*2 + w;

    for (int i = t; i < K*O/4; i += 128)
        ((float4*)wt)[i] = ((const float4*)Wt)[i];
    for (int i = lane; i < 32*G; i += 64){
        int b = i / G, g = i - b*G;
        float f[8];
        if (EXTIN && f32){
            const float* src = (const float*)xin + ((size_t)b*NN + n)*K + g*8;
            float4 v0 = ((const float4*)src)[0];
            float4 v1 = ((const float4*)src)[1];
            f[0]=v0.x; f[1]=v0.y; f[2]=v0.z; f[3]=v0.w;
            f[4]=v1.x; f[5]=v1.y; f[6]=v1.z; f[7]=v1.w;
        } else {
            uint4 v = *(const uint4*)((const ushort_t*)xin + ((size_t)b*NN + n)*K + (size_t)g*8);
            unpack8(v, f);
        }
        #pragma unroll
        for (int j=0;j<8;j++) xst[w][(g*8+j)*36 + b] = f[j];
    }
    __syncthreads();

    int bt = lane % NBT, jt = lane / NBT;
    int b0 = bt*BR, j0 = jt*8;
    const float* xw = xst[w];
    float acc[BR][8];
    #pragma unroll
    for (int i=0;i<BR;i++)
        #pragma unroll
        for (int j=0;j<8;j++) acc[i][j] = 0.f;

    for (int k = 0; k < K; k++){
        float xv[BR], wv[8];
        #pragma unroll
        for (int i=0;i<BR;i+=4)
            *(float4*)&xv[i] = *(const float4*)&xw[k*36 + b0 + i];
        *(float4*)&wv[0] = *(const float4*)&wt[k*O + j0];
        *(float4*)&wv[4] = *(const float4*)&wt[k*O + j0 + 4];
        #pragma unroll
        for (int i=0;i<BR;i++)
            #pragma unroll
            for (int j=0;j<8;j++) acc[i][j] = fmaf(xv[i], wv[j], acc[i][j]);
    }

    float bj[8];
    #pragma unroll
    for (int j=0;j<8;j++) bj[j] = ldin(bias, j0+j, f32);
    float s1 = 0.f, s2 = 0.f;
    #pragma unroll
    for (int i=0;i<BR;i++)
        #pragma unroll
        for (int j=0;j<8;j++){
            float a = acc[i][j] + bj[j];
            acc[i][j] = a; s1 += a; s2 = fmaf(a, a, s2);
        }
    #pragma unroll
    for (int off = 32; off > 0; off >>= 1){
        s1 += __shfl_down(s1, off);
        s2 += __shfl_down(s2, off);
    }
    s1 = __shfl(s1, 0); s2 = __shfl(s2, 0);
    const float M = 32.f * O;
    float m  = s1 / M;
    float vv = s2 / M - m*m;
    float rs = rsqrtf(vv + 1e-5f);
    float gv = ldin(bng, n, f32), bv = ldin(bnb, n, f32);
    #pragma unroll
    for (int i=0;i<BR;i++){
        union { uint4 u; ushort_t s[8]; } pk;
        #pragma unroll
        for (int j=0;j<8;j++)
            pk.s[j] = f2bf(fmaxf(fmaf(gv*(acc[i][j]-m), rs, bv), 0.f));
        *(uint4*)(out + ((size_t)(b0+i)*NN + n)*O + j0) = pk.u;
    }
}

// ---------------- shared tails for the fused MFMA kernels ------------------
// Block owns rows [row0, row0+64).  Lane owns values at (r = m*16+quad*4+reg,
// n = w*32+nt*16+col).  xs: 16 KB A-layout buffer (reused for u), xt: 16 KB
// [c][64r] transpose of x'.

__device__ __forceinline__ void tail_stage_x(ushort_t* xs, ushort_t* xt,
                                             const float o[2][16],
                                             int w, int col, int quad){
    #pragma unroll
    for (int nt=0;nt<2;nt++){
        int n = w*32 + nt*16 + col;
        #pragma unroll
        for (int m=0;m<4;m++){
            union { uint2 u2; ushort_t s[4]; } pk;
            #pragma unroll
            for (int reg=0;reg<4;reg++){
                int r = m*16 + quad*4 + reg;
                ushort_t hv = f2bf(o[nt][m*4+reg]);
                xs[((n>>3)*64 + r)*8 + (n&7)] = hv;   // A-layout (for lin/writeA)
                pk.s[reg] = hv;
            }
            *(uint2*)&xt[n*64 + m*16 + quad*4] = pk.u2;   // [c][64r] for Tp
        }
    }
}

__device__ __forceinline__ void tail_write_A(const ushort_t* xs, ushort_t* A,
                                             size_t row0, int t){
    uint4* dst = (uint4*)(A + row0*128);
    #pragma unroll
    for (int c = 0; c < 4; c++){
        int i = t + c*256;
        int r = i >> 4, kg = i & 15;
        dst[i] = *(const uint4*)&xs[(kg*64 + r)*8];
    }
}

// next linear: U = relu(x'·W^T + b) -> UT; dvec; then the block's 64-row
// T-partial  Tp[s][b][n][c] = sum_r u[r][n] * x'[r][c]  (fp32, via MFMA).
__device__ __forceinline__ void tail_lin_relu_T(ushort_t* xs, ushort_t* xt,
    ushort_t* UT, const ushort_t* Whi, const ushort_t* Wlo, const void* bias,
    float* dvec, float* Tp,
    size_t row0, int b, int rbase, int t, int w, int col, int quad, int f32)
{
    if (t < 64){
        float s = 0.f;
        #pragma unroll 8
        for (int k=0;k<128;k++){
            float v = bf2f(xs[((k>>3)*64 + t)*8 + (k&7)]);
            s = fmaf(v, v, s);
        }
        dvec[row0 + t] = s;
    }
    v4f acc[4][2];
    #pragma unroll
    for (int m=0;m<4;m++)
        #pragma unroll
        for (int nt=0;nt<2;nt++) acc[m][nt] = (v4f){0.f,0.f,0.f,0.f};
    #pragma unroll
    for (int kt = 0; kt < 4; kt++){
        int kg = kt*4 + quad;
        v8s a[4], bh[2], bl[2];
        #pragma unroll
        for (int nt=0;nt<2;nt++){
            int n = w*32 + nt*16 + col;
            bh[nt] = *(const v8s*)&Whi[(kg*128 + n)*8];
            bl[nt] = *(const v8s*)&Wlo[(kg*128 + n)*8];
        }
        #pragma unroll
        for (int m=0;m<4;m++)
            a[m] = *(const v8s*)&xs[(kg*64 + m*16 + col)*8];
        #pragma unroll
        for (int m=0;m<4;m++)
            #pragma unroll
            for (int nt=0;nt<2;nt++){
                acc[m][nt] = MFMA_BF16(a[m], bh[nt], acc[m][nt], 0, 0, 0);
                acc[m][nt] = MFMA_BF16(a[m], bl[nt], acc[m][nt], 0, 0, 0);
            }
    }
    float u[2][16];
    #pragma unroll
    for (int nt=0;nt<2;nt++){
        int n = w*32 + nt*16 + col;
        float bn = ldin(bias, n, f32);
        #pragma unroll
        for (int m=0;m<4;m++)
            #pragma unroll
            for (int reg=0;reg<4;reg++)
                u[nt][m*4+reg] = fmaxf(acc[m][nt][reg] + bn, 0.f);
    }
    __syncthreads();           // xs reads (a-frags, dvec) done
    #pragma unroll
    for (int nt=0;nt<2;nt++){
        int n = w*32 + nt*16 + col;
        #pragma unroll
        for (int m=0;m<4;m++){
            union { uint2 u2; ushort_t s[4]; } pk;
            #pragma unroll
            for (int reg=0;reg<4;reg++)
                pk.s[reg] = f2bf(u[nt][m*4+reg]);
            *(uint2*)&xs[n*64 + m*16 + quad*4] = pk.u2;   // u in [n][64r]
        }
    }
    __syncthreads();
    #pragma unroll
    for (int c = 0; c < 4; c++){
        int i = t + c*256;
        int n = i >> 3, sg = i & 7;
        *(uint4*)&UT[((size_t)b*128 + n)*1024 + rbase + sg*8] =
            *(const uint4*)&xs[n*64 + sg*8];
    }
    // ---- T-partial over own 64 rows: A = u [n][r], B = x' [c][r] ----
    v4f tacc[4][4];
    #pragma unroll
    for (int m=0;m<4;m++)
        #pragma unroll
        for (int q=0;q<4;q++) tacc[m][q] = (v4f){0.f,0.f,0.f,0.f};
    int wn = (w & 1)*64, wc = (w >> 1)*64;
    #pragma unroll
    for (int kt = 0; kt < 2; kt++){
        int kg = kt*4 + quad;
        v8s a[4], bb[4];
        #pragma unroll
        for (int m=0;m<4;m++)
            a[m] = *(const v8s*)&xs[(wn + m*16 + col)*64 + kg*8];
        #pragma unroll
        for (int q=0;q<4;q++)
            bb[q] = *(const v8s*)&xt[(wc + q*16 + col)*64 + kg*8];
        #pragma unroll
        for (int m=0;m<4;m++)
            #pragma unroll
            for (int q=0;q<4;q++)
                tacc[m][q] = MFMA_BF16(a[m], bb[q], tacc[m][q], 0, 0, 0);
    }
    int s16 = (int)((row0 >> 6) & 15);
    float* dst = Tp + ((size_t)(s16*NB + b) << 14);
    #pragma unroll
    for (int m=0;m<4;m++)
        #pragma unroll
        for (int q=0;q<4;q++)
            #pragma unroll
            for (int reg=0;reg<4;reg++){
                int n = wn + m*16 + quad*4 + reg;
                int c = wc + q*16 + col;
                dst[n*128 + c] = tacc[m][q][reg];
            }
}

// ---------------- fused: enc3 sigmoid + relation-1 U + T-partial -----------
__global__ __launch_bounds__(256) void k_linfuse0(
    const ushort_t* __restrict__ xin,                 // E2, row-major
    const ushort_t* __restrict__ W3h, const ushort_t* __restrict__ W3l,
    const void* __restrict__ b3,
    const ushort_t* __restrict__ W1h, const ushort_t* __restrict__ W1l,
    const void* __restrict__ b1,
    ushort_t* __restrict__ A, ushort_t* __restrict__ UT,
    float* __restrict__ dvec, float* __restrict__ Tp,
    const void* __restrict__ detin)
{
    __shared__ __align__(16) ushort_t xs[8192];
    __shared__ __align__(16) ushort_t xt[8192];
    int f32 = detect_dev(detin);
    int t = threadIdx.x;
    size_t row0 = (size_t)blockIdx.x * 64;
    int b = (int)(row0 >> 10), rbase = (int)(row0 & 1023);
    {
        const uint4* src = (const uint4*)(xin + row0*128);
        #pragma unroll
        for (int c = 0; c < 4; c++){
            int i = t + c*256;
            int r = i >> 4, kg = i & 15;
            *(uint4*)&xs[(kg*64 + r)*8] = src[i];
        }
    }
    __syncthreads();
    int w = t >> 6, lane = t & 63;
    int col = lane & 15, quad = lane >> 4;
    v4f acc[4][2];
    #pragma unroll
    for (int m=0;m<4;m++)
        #pragma unroll
        for (int nt=0;nt<2;nt++) acc[m][nt] = (v4f){0.f,0.f,0.f,0.f};
    #pragma unroll
    for (int kt = 0; kt < 4; kt++){
        int kg = kt*4 + quad;
        v8s a[4], bh[2], bl[2];
        #pragma unroll
        for (int nt=0;nt<2;nt++){
            int n = w*32 + nt*16 + col;
            bh[nt] = *(const v8s*)&W3h[(kg*128 + n)*8];
            bl[nt] = *(const v8s*)&W3l[(kg*128 + n)*8];
        }
        #pragma unroll
        for (int m=0;m<4;m++)
            a[m] = *(const v8s*)&xs[(kg*64 + m*16 + col)*8];
        #pragma unroll
        for (int m=0;m<4;m++)
            #pragma unroll
            for (int nt=0;nt<2;nt++){
                acc[m][nt] = MFMA_BF16(a[m], bh[nt], acc[m][nt], 0, 0, 0);
                acc[m][nt] = MFMA_BF16(a[m], bl[nt], acc[m][nt], 0, 0, 0);
            }
    }
    float o[2][16];
    #pragma unroll
    for (int nt=0;nt<2;nt++){
        int n = w*32 + nt*16 + col;
        float bn = ldin(b3, n, f32);
        #pragma unroll
        for (int m=0;m<4;m++)
            #pragma unroll
            for (int reg=0;reg<4;reg++){
                float v = acc[m][nt][reg] + bn;
                o[nt][m*4+reg] = 1.f/(1.f+expf(-v));
            }
    }
    __syncthreads();
    tail_stage_x(xs, xt, o, w, col, quad);
    __syncthreads();
    tail_write_A(xs, A, row0, t);
    tail_lin_relu_T(xs, xt, UT, W1h, W1l, b1, dvec, Tp,
                    row0, b, rbase, t, w, col, quad, f32);
}

// ---------------- reduce 16 partials -> Tt hi/lo (MFMA-B layout) -----------
__global__ __launch_bounds__(256) void k_tred(const float* __restrict__ Tp,
                                              ushort_t* __restrict__ Thi, ushort_t* __restrict__ Tlo){
    int i = blockIdx.x*256 + threadIdx.x;
    const size_t S = 524288;
    float s = 0.f;
    #pragma unroll
    for (int k = 0; k < 16; k++) s += Tp[(size_t)k*S + i];
    int bb = i >> 14, j = i & 16383;
    int n = j >> 7, c = j & 127;
    int di = (bb << 14) + ((c >> 3)*128 + n)*8 + (c & 7);
    ushort_t h = f2bf(s);
    Thi[di] = h;
    Tlo[di] = f2bf(s - bf2f(h));
}

// ---------------- fused: relout_r (+ lin_{r+1} + T-partial unless LAST) ----
template<int LAST>
__global__ __launch_bounds__(256) void k_relfuse(
    ushort_t* __restrict__ x, ushort_t* __restrict__ UT,
    const ushort_t* __restrict__ Thi, const ushort_t* __restrict__ Tlo,
    float* __restrict__ dvec,
    const void* __restrict__ psi, const void* __restrict__ phi, const void* __restrict__ wr,
    const ushort_t* __restrict__ Wnh, const ushort_t* __restrict__ Wnl,
    const void* __restrict__ bnext, float* __restrict__ Tp,
    const void* __restrict__ detin)
{
    __shared__ __align__(16) ushort_t xs[8192];
    __shared__ __align__(16) ushort_t xt[8192];
    int f32 = detect_dev(detin);
    int t = threadIdx.x;
    size_t row0 = (size_t)blockIdx.x * 64;
    int b = (int)(row0 >> 10), rbase = (int)(row0 & 1023);
    {
        const uint4* src = (const uint4*)(x + row0*128);
        #pragma unroll
        for (int c = 0; c < 4; c++){
            int i = t + c*256;
            int r = i >> 4, kg = i & 15;
            *(uint4*)&xs[(kg*64 + r)*8] = src[i];
        }
    }
    __syncthreads();
    float alpha = ldin(wr,0,f32) * ldin(psi,0,f32) * ldin(phi,0,f32) * (1.f/1024.f);
    int w = t >> 6, lane = t & 63;
    int col = lane & 15, quad = lane >> 4;
    const ushort_t* sh = Thi + ((size_t)b << 14);
    const ushort_t* sl = Tlo + ((size_t)b << 14);
    v4f acc[4][2];
    #pragma unroll
    for (int m=0;m<4;m++)
        #pragma unroll
        for (int nt=0;nt<2;nt++) acc[m][nt] = (v4f){0.f,0.f,0.f,0.f};
    #pragma unroll
    for (int kt = 0; kt < 4; kt++){
        int kg = kt*4 + quad;
        v8s a[4], bh[2], bl[2];
        #pragma unroll
        for (int nt=0;nt<2;nt++){
            int n = w*32 + nt*16 + col;
            bh[nt] = *(const v8s*)&sh[(kg*128 + n)*8];
            bl[nt] = *(const v8s*)&sl[(kg*128 + n)*8];
        }
        #pragma unroll
        for (int m=0;m<4;m++)
            a[m] = *(const v8s*)&xs[(kg*64 + m*16 + col)*8];
        #pragma unroll
        for (int m=0;m<4;m++)
            #pragma unroll
            for (int nt=0;nt<2;nt++){
                acc[m][nt] = MFMA_BF16(a[m], bh[nt], acc[m][nt], 0, 0, 0);
                acc[m][nt] = MFMA_BF16(a[m], bl[nt], acc[m][nt], 0, 0, 0);
            }
    }
    float o[2][16];
    #pragma unroll
    for (int m=0;m<4;m++){
        float4 d4 = *(const float4*)&dvec[row0 + m*16 + quad*4];
        const float* dr = (const float*)&d4;
        #pragma unroll
        for (int nt=0;nt<2;nt++){
            int n = w*32 + nt*16 + col;
            uint2 uu = *(const uint2*)&UT[((size_t)b*128 + n)*1024 + rbase + m*16 + quad*4];
            float uf[4];
            uf[0] = __uint_as_float(uu.x << 16);
            uf[1] = __uint_as_float(uu.x & 0xffff0000u);
            uf[2] = __uint_as_float(uu.y << 16);
            uf[3] = __uint_as_float(uu.y & 0xffff0000u);
            #pragma unroll
            for (int reg=0;reg<4;reg++){
                int r = m*16 + quad*4 + reg;
                float xv = bf2f(xs[((n>>3)*64 + r)*8 + (n&7)]);
                o[nt][m*4+reg] = fmaf(alpha, acc[m][nt][reg] - dr[reg]*uf[reg], xv);
            }
        }
    }
    __syncthreads();           // all xs / dvec / UT reads done
    tail_stage_x(xs, xt, o, w, col, quad);
    __syncthreads();
    tail_write_A(xs, x, row0, t);
    if (!LAST)
        tail_lin_relu_T(xs, xt, UT, Wnh, Wnl, bnext, dvec, Tp,
                        row0, b, rbase, t, w, col, quad, f32);
}

// ---------------- decoder tail ---------------------------------------------
__global__ __launch_bounds__(256) void k_dec2(
    const ushort_t* __restrict__ x,       // [B,N,64]
    const float* __restrict__ W2t, const void* __restrict__ b2,
    const float* __restrict__ Wct, const void* __restrict__ bcb,
    const float* __restrict__ Wgt, const void* __restrict__ bgb,
    void* __restrict__ out, const void* __restrict__ detin)
{
    int f32 = detect_dev(detin);
    __shared__ __align__(16) float w2[64*32];
    __shared__ __align__(16) float wc[32*28];
    __shared__ __align__(16) float wg[32*4];
    __shared__ __align__(16) float xsd[8][64];
    __shared__ float hs[8][33];
    size_t row0 = (size_t)blockIdx.x * 8;
    int t = threadIdx.x;
    for (int i=t;i<512;i+=256)  ((float4*)w2)[i] = ((const float4*)W2t)[i];
    if (t < 224) ((float4*)wc)[t] = ((const float4*)Wct)[t];
    if (t < 32)  ((float4*)wg)[t] = ((const float4*)Wgt)[t];
    if (t < 64){
        int row = t >> 3, seg = t & 7;
        uint4 v = *(const uint4*)&x[(row0 + row)*64 + seg*8];
        float f[8]; unpack8(v, f);
        *(float4*)&xsd[row][seg*8]   = make_float4(f[0],f[1],f[2],f[3]);
        *(float4*)&xsd[row][seg*8+4] = make_float4(f[4],f[5],f[6],f[7]);
    }
    __syncthreads();
    int j = t & 31, r = t >> 5;
    float a = ldin(b2, j, f32);
    #pragma unroll 8
    for (int k=0;k<64;k++) a = fmaf(xsd[r][k], w2[k*32 + j], a);
    hs[r][j] = fmaxf(a, 0.f);
    __syncthreads();
    float o;
    if (j < 28){
        o = ldin(bcb, j, f32);
        #pragma unroll
        for (int k=0;k<32;k++) o = fmaf(hs[r][k], wc[k*28 + j], o);
    } else {
        int jj = j - 28;
        o = ldin(bgb, jj, f32);
        #pragma unroll
        for (int k=0;k<32;k++) o = fmaf(hs[r][k], wg[k*4 + jj], o);
    }
    size_t oi = (row0 + r)*32 + j;
    if (f32) ((float*)out)[oi] = o;
    else     ((ushort_t*)out)[oi] = f2bf(o);
}

// ---------------------------------------------------------------------------
enum { O_E1=0, O_E2=2048, O_D1=10240, O_D2=18432, O_BC=20480, O_BG=21376 };

extern "C" void kernel_launch(void* const* d_in, const int* in_sizes, int n_in,
                              void* d_out, int out_size, void* d_ws, size_t ws_size,
                              hipStream_t stream)
{
    (void)in_sizes; (void)n_in; (void)out_size; (void)ws_size;
    const void* input = d_in[0];
    const void* e1_W = d_in[1];  const void* e1_b = d_in[2];
    const void* bn1_g = d_in[3]; const void* bn1_b = d_in[4];
    const void* e2_W = d_in[5];  const void* e2_b = d_in[6];
    const void* bn2_g = d_in[7]; const void* bn2_b = d_in[8];
    const void* e3_W = d_in[9];  const void* e3_b = d_in[10];
    const void *rW[4], *rb[4], *rpsi[4], *rphi[4], *rwr[4];
    for (int r = 0; r < 4; r++){
        rW[r]   = d_in[11 + r*5 + 0];
        rb[r]   = d_in[11 + r*5 + 1];
        rpsi[r] = d_in[11 + r*5 + 2];
        rphi[r] = d_in[11 + r*5 + 3];
        rwr[r]  = d_in[11 + r*5 + 4];
    }
    const void* d1_W = d_in[31]; const void* d1_b = d_in[32];
    const void* dbn_g = d_in[33];const void* dbn_b = d_in[34];
    const void* d2_W = d_in[35]; const void* d2_b = d_in[36];
    const void* bc_W = d_in[37]; const void* bc_b = d_in[38];
    const void* bg_W = d_in[39]; const void* bg_b = d_in[40];

    // ---- workspace layout (61.4 MB), float offsets (all 16B-aligned) ----
    float*    ws_f = (float*)d_ws;
    float*    wpf  = ws_f;                          // 21504 f
    float*    dd   = ws_f + 21504;                  // 32768 f
    ushort_t* whi  = (ushort_t*)(ws_f + 54272);     // 5*16384 us
    ushort_t* wlo  = (ushort_t*)(ws_f + 95232);     // 5*16384 us
    ushort_t* Thi  = (ushort_t*)(ws_f + 136192);    // 524288 us
    ushort_t* Tlo  = (ushort_t*)(ws_f + 398336);    // 524288 us
    float*    Tp   = ws_f + 660480;                 // 16*32*16384 = 8388608 f
    ushort_t* A    = (ushort_t*)(ws_f + 9049088);   // [32768][128] bf16
    ushort_t* UT   = (ushort_t*)(ws_f + 11146240);  // [32][128][1024] bf16
    ushort_t* E2   = (ushort_t*)(ws_f + 13243392);  // [32768][128] bf16
    ushort_t* Cenc = A;                             // [32768][64] overlays A
    ushort_t* Cdec = UT;                            // [32768][64] overlays UT

    PrepArgs pa;
    const void* srcs[11] = {e1_W, e2_W, d1_W, d2_W, bc_W, bg_W,
                            e3_W, rW[0], rW[1], rW[2], rW[3]};
    const int  Ks[11]   = {32,64,128,64,32,32, 128,128,128,128,128};
    const int  Os[11]   = {64,128,64,32,28,4,  128,128,128,128,128};
    const int  offs[11] = {O_E1,O_E2,O_D1,O_D2,O_BC,O_BG, 0,0,0,0,0};
    for (int i=0;i<11;i++){ pa.w[i]=srcs[i]; pa.K[i]=Ks[i]; pa.O[i]=Os[i]; pa.off[i]=offs[i]; }

    k_prep<<<dim3(64,11), 256, 0, stream>>>(pa, wpf, whi, wlo, input);
    k_bnlin<32,64,true><<<512, 128, 0, stream>>>(input, wpf+O_E1, e1_b, bn1_g, bn1_b, Cenc, input);
    k_bnlin<64,128,false><<<512, 128, 0, stream>>>(Cenc, wpf+O_E2, e2_b, bn2_g, bn2_b, E2, input);
    k_linfuse0<<<512, 256, 0, stream>>>(E2, whi, wlo, e3_b,
                                        whi + 16384, wlo + 16384, rb[0],
                                        A, UT, dd, Tp, input);

    for (int r = 0; r < 4; r++){
        k_tred<<<2048, 256, 0, stream>>>(Tp, Thi, Tlo);
        if (r < 3)
            k_relfuse<0><<<512, 256, 0, stream>>>(A, UT, Thi, Tlo, dd,
                rpsi[r], rphi[r], rwr[r],
                whi + (size_t)(2+r)*16384, wlo + (size_t)(2+r)*16384, rb[r+1], Tp, input);
        else
            k_relfuse<1><<<512, 256, 0, stream>>>(A, UT, Thi, Tlo, dd,
                rpsi[r], rphi[r], rwr[r], whi, wlo, rb[r], Tp, input);
    }

    k_bnlin<128,64,false><<<512, 128, 0, stream>>>(A, wpf+O_D1, d1_b, dbn_g, dbn_b, Cdec, input);
    k_dec2<<<4096, 256, 0, stream>>>(Cdec, wpf+O_D2, d2_b, wpf+O_BC, bc_b, wpf+O_BG, bg_b, d_out, input);
}

// Round 11
// 319.989 us; speedup vs baseline: 5.3703x; 1.0199x over previous
//
#include <hip/hip_runtime.h>
#include <hip/hip_bf16.h>

// ---------------------------------------------------------------------------
// Generator_58737972740271.  R11 (from R10): Tp partials stored as bf16 in
// [c][n] layout with packed uint2 stores (was 64 scattered fp32 dwords/lane);
// k_tred reads 16 MB (was 32) with uint4-coalesced Thi/Tlo writes; k_dec2
// 512 blocks x 8-tile loop (weights loaded once).  Everything else identical.
// ---------------------------------------------------------------------------

typedef __hip_bfloat16 bf16;
typedef unsigned short ushort_t;
typedef float v4f __attribute__((ext_vector_type(4)));
typedef short v8s __attribute__((ext_vector_type(8)));
#define MFMA_BF16 __builtin_amdgcn_mfma_f32_16x16x32_bf16

#define NB 32
#define NN 1024

__device__ __forceinline__ float ldin(const void* p, size_t i, int f32){
    return f32 ? ((const float*)p)[i] : __bfloat162float(((const bf16*)p)[i]);
}
__device__ __forceinline__ float bf2f(ushort_t u){
    return __uint_as_float((unsigned)u << 16);
}
__device__ __forceinline__ ushort_t f2bf(float v){
    bf16 h = __float2bfloat16(v);
    ushort_t s; __builtin_memcpy(&s, &h, 2);
    return s;
}
__device__ __forceinline__ void unpack8(uint4 v, float* f){
    f[0] = __uint_as_float(v.x << 16);
    f[1] = __uint_as_float(v.x & 0xffff0000u);
    f[2] = __uint_as_float(v.y << 16);
    f[3] = __uint_as_float(v.y & 0xffff0000u);
    f[4] = __uint_as_float(v.z << 16);
    f[5] = __uint_as_float(v.z & 0xffff0000u);
    f[6] = __uint_as_float(v.w << 16);
    f[7] = __uint_as_float(v.w & 0xffff0000u);
}

__device__ __forceinline__ int detect_dev(const void* inp){
    __shared__ int sflag;
    int t = threadIdx.x;
    if (t < 64){
        unsigned v = ((const unsigned*)inp)[t];
        unsigned long long m = __ballot((v & 0x80008000u) != 0u);
        if (t == 0) sflag = (__popcll(m) > 4) ? 1 : 0;
    }
    __syncthreads();
    return sflag;
}

// ---------------- prep: weights --------------------------------------------
struct PrepArgs {
    const void* w[11];
    int K[11], O[11], off[11];
};

__global__ __launch_bounds__(256) void k_prep(PrepArgs a, float* __restrict__ wpf,
                                              ushort_t* __restrict__ whi, ushort_t* __restrict__ wlo,
                                              const void* __restrict__ detin){
    int f32 = detect_dev(detin);
    int s = blockIdx.y;
    int idx = blockIdx.x*256 + threadIdx.x;
    if (s < 6){
        int K = a.K[s], O = a.O[s];
        if (idx >= K*O) return;
        int k = idx / O, j = idx - k*O;
        wpf[a.off[s] + idx] = ldin(a.w[s], (size_t)j*K + k, f32);
    } else {
        if (idx >= 16384) return;
        int n = idx >> 7, k = idx & 127;
        float v = ldin(a.w[s], (size_t)n*128 + k, f32);
        ushort_t h = f2bf(v);
        ushort_t l = f2bf(v - bf2f(h));
        int di = (s - 6)*16384 + ((k >> 3)*128 + n)*8 + (k & 7);
        whi[di] = h; wlo[di] = l;
    }
}

// ---------------- fused linear + BatchNorm(channel=n) + ReLU (VALU) --------
template<int K, int O, bool EXTIN>
__global__ __launch_bounds__(128) void k_bnlin(
    const void* __restrict__ xin, const float* __restrict__ Wt,
    const void* __restrict__ bias, const void* __restrict__ bng,
    const void* __restrict__ bnb, ushort_t* __restrict__ out,
    const void* __restrict__ detin)
{
    int f32 = detect_dev(detin);
    constexpr int BR  = O/16;
    constexpr int NBT = 32/BR;
    constexpr int G   = K/8;
    __shared__ __align__(16) float wt[K*O];
    __shared__ __align__(16) float xst[2][K*36];
    int t = threadIdx.x;
    int w = t >> 6, lane = t & 63;
    int n = blockIdx.x*2 + w;

    for (int i = t; i < K*O/4; i += 128)
        ((float4*)wt)[i] = ((const float4*)Wt)[i];
    for (int i = lane; i < 32*G; i += 64){
        int b = i / G, g = i - b*G;
        float f[8];
        if (EXTIN && f32){
            const float* src = (const float*)xin + ((size_t)b*NN + n)*K + g*8;
            float4 v0 = ((const float4*)src)[0];
            float4 v1 = ((const float4*)src)[1];
            f[0]=v0.x; f[1]=v0.y; f[2]=v0.z; f[3]=v0.w;
            f[4]=v1.x; f[5]=v1.y; f[6]=v1.z; f[7]=v1.w;
        } else {
            uint4 v = *(const uint4*)((const ushort_t*)xin + ((size_t)b*NN + n)*K + (size_t)g*8);
            unpack8(v, f);
        }
        #pragma unroll
        for (int j=0;j<8;j++) xst[w][(g*8+j)*36 + b] = f[j];
    }
    __syncthreads();

    int bt = lane % NBT, jt = lane / NBT;
    int b0 = bt*BR, j0 = jt*8;
    const float* xw = xst[w];
    float acc[BR][8];
    #pragma unroll
    for (int i=0;i<BR;i++)
        #pragma unroll
        for (int j=0;j<8;j++) acc[i][j] = 0.f;

    for (int k = 0; k < K; k++){
        float xv[BR], wv[8];
        #pragma unroll
        for (int i=0;i<BR;i+=4)
            *(float4*)&xv[i] = *(const float4*)&xw[k*36 + b0 + i];
        *(float4*)&wv[0] = *(const float4*)&wt[k*O + j0];
        *(float4*)&wv[4] = *(const float4*)&wt[k*O + j0 + 4];
        #pragma unroll
        for (int i=0;i<BR;i++)
            #pragma unroll
            for (int j=0;j<8;j++) acc[i][j] = fmaf(xv[i], wv[j], acc[i][j]);
    }

    float bj[8];
    #pragma unroll
    for (int j=0;j<8;j++) bj[j] = ldin(bias, j0+j, f32);
    float s1 = 0.f, s2 = 0.f;
    #pragma unroll
    for (int i=0;i<BR;i++)
        #pragma unroll
        for (int j=0;j<8;j++){
            float a = acc[i][j] + bj[j];
            acc[i][j] = a; s1 += a; s2 = fmaf(a, a, s2);
        }
    #pragma unroll
    for (int off = 32; off > 0; off >>= 1){
        s1 += __shfl_down(s1, off);
        s2 += __shfl_down(s2, off);
    }
    s1 = __shfl(s1, 0); s2 = __shfl(s2, 0);
    const float M = 32.f * O;
    float m  = s1 / M;
    float vv = s2 / M - m*m;
    float rs = rsqrtf(vv + 1e-5f);
    float gv = ldin(bng, n, f32), bv = ldin(bnb, n, f32);
    #pragma unroll
    for (int i=0;i<BR;i++){
        union { uint4 u; ushort_t s[8]; } pk;
        #pragma unroll
        for (int j=0;j<8;j++)
            pk.s[j] = f2bf(fmaxf(fmaf(gv*(acc[i][j]-m), rs, bv), 0.f));
        *(uint4*)(out + ((size_t)(b0+i)*NN + n)*O + j0) = pk.u;
    }
}

// ---------------- shared tails for the fused MFMA kernels ------------------
// Block owns rows [row0, row0+64).  Lane owns values at (r = m*16+quad*4+reg,
// n = w*32+nt*16+col).  xs: A-layout buffer (reused for u), xt: [c][64r].

__device__ __forceinline__ void tail_stage_x(ushort_t* xs, ushort_t* xt,
                                             const float o[2][16],
                                             int w, int col, int quad){
    #pragma unroll
    for (int nt=0;nt<2;nt++){
        int n = w*32 + nt*16 + col;
        #pragma unroll
        for (int m=0;m<4;m++){
            union { uint2 u2; ushort_t s[4]; } pk;
            #pragma unroll
            for (int reg=0;reg<4;reg++){
                int r = m*16 + quad*4 + reg;
                ushort_t hv = f2bf(o[nt][m*4+reg]);
                xs[((n>>3)*64 + r)*8 + (n&7)] = hv;
                pk.s[reg] = hv;
            }
            *(uint2*)&xt[n*64 + m*16 + quad*4] = pk.u2;
        }
    }
}

__device__ __forceinline__ void tail_write_A(const ushort_t* xs, ushort_t* A,
                                             size_t row0, int t){
    uint4* dst = (uint4*)(A + row0*128);
    #pragma unroll
    for (int c = 0; c < 4; c++){
        int i = t + c*256;
        int r = i >> 4, kg = i & 15;
        dst[i] = *(const uint4*)&xs[(kg*64 + r)*8];
    }
}

// next linear: U = relu(x'·W^T + b) -> UT; dvec; then the block's 64-row
// T-partial  Tp[s][b][c][n] (bf16) = sum_r u[r][n] * x'[r][c]  via MFMA.
__device__ __forceinline__ void tail_lin_relu_T(ushort_t* xs, ushort_t* xt,
    ushort_t* UT, const ushort_t* Whi, const ushort_t* Wlo, const void* bias,
    float* dvec, ushort_t* Tp,
    size_t row0, int b, int rbase, int t, int w, int col, int quad, int f32)
{
    if (t < 64){
        float s = 0.f;
        #pragma unroll 8
        for (int k=0;k<128;k++){
            float v = bf2f(xs[((k>>3)*64 + t)*8 + (k&7)]);
            s = fmaf(v, v, s);
        }
        dvec[row0 + t] = s;
    }
    v4f acc[4][2];
    #pragma unroll
    for (int m=0;m<4;m++)
        #pragma unroll
        for (int nt=0;nt<2;nt++) acc[m][nt] = (v4f){0.f,0.f,0.f,0.f};
    #pragma unroll
    for (int kt = 0; kt < 4; kt++){
        int kg = kt*4 + quad;
        v8s a[4], bh[2], bl[2];
        #pragma unroll
        for (int nt=0;nt<2;nt++){
            int n = w*32 + nt*16 + col;
            bh[nt] = *(const v8s*)&Whi[(kg*128 + n)*8];
            bl[nt] = *(const v8s*)&Wlo[(kg*128 + n)*8];
        }
        #pragma unroll
        for (int m=0;m<4;m++)
            a[m] = *(const v8s*)&xs[(kg*64 + m*16 + col)*8];
        #pragma unroll
        for (int m=0;m<4;m++)
            #pragma unroll
            for (int nt=0;nt<2;nt++){
                acc[m][nt] = MFMA_BF16(a[m], bh[nt], acc[m][nt], 0, 0, 0);
                acc[m][nt] = MFMA_BF16(a[m], bl[nt], acc[m][nt], 0, 0, 0);
            }
    }
    float u[2][16];
    #pragma unroll
    for (int nt=0;nt<2;nt++){
        int n = w*32 + nt*16 + col;
        float bn = ldin(bias, n, f32);
        #pragma unroll
        for (int m=0;m<4;m++)
            #pragma unroll
            for (int reg=0;reg<4;reg++)
                u[nt][m*4+reg] = fmaxf(acc[m][nt][reg] + bn, 0.f);
    }
    __syncthreads();           // xs reads (a-frags, dvec) done
    #pragma unroll
    for (int nt=0;nt<2;nt++){
        int n = w*32 + nt*16 + col;
        #pragma unroll
        for (int m=0;m<4;m++){
            union { uint2 u2; ushort_t s[4]; } pk;
            #pragma unroll
            for (int reg=0;reg<4;reg++)
                pk.s[reg] = f2bf(u[nt][m*4+reg]);
            *(uint2*)&xs[n*64 + m*16 + quad*4] = pk.u2;   // u in [n][64r]
        }
    }
    __syncthreads();
    #pragma unroll
    for (int c = 0; c < 4; c++){
        int i = t + c*256;
        int n = i >> 3, sg = i & 7;
        *(uint4*)&UT[((size_t)b*128 + n)*1024 + rbase + sg*8] =
            *(const uint4*)&xs[n*64 + sg*8];
    }
    // ---- T-partial over own 64 rows: A = u [n][r], B = x' [c][r] ----
    v4f tacc[4][4];
    #pragma unroll
    for (int m=0;m<4;m++)
        #pragma unroll
        for (int q=0;q<4;q++) tacc[m][q] = (v4f){0.f,0.f,0.f,0.f};
    int wn = (w & 1)*64, wc = (w >> 1)*64;
    #pragma unroll
    for (int kt = 0; kt < 2; kt++){
        int kg = kt*4 + quad;
        v8s a[4], bb[4];
        #pragma unroll
        for (int m=0;m<4;m++)
            a[m] = *(const v8s*)&xs[(wn + m*16 + col)*64 + kg*8];
        #pragma unroll
        for (int q=0;q<4;q++)
            bb[q] = *(const v8s*)&xt[(wc + q*16 + col)*64 + kg*8];
        #pragma unroll
        for (int m=0;m<4;m++)
            #pragma unroll
            for (int q=0;q<4;q++)
                tacc[m][q] = MFMA_BF16(a[m], bb[q], tacc[m][q], 0, 0, 0);
    }
    int s16 = (int)((row0 >> 6) & 15);
    ushort_t* dst = Tp + ((size_t)(s16*NB + b) << 14);   // [c][n] bf16
    #pragma unroll
    for (int m=0;m<4;m++)
        #pragma unroll
        for (int q=0;q<4;q++){
            int c = wc + q*16 + col;
            union { uint2 u2; ushort_t s[4]; } pk;
            #pragma unroll
            for (int reg=0;reg<4;reg++)
                pk.s[reg] = f2bf(tacc[m][q][reg]);       // n-consecutive
            *(uint2*)&dst[c*128 + wn + m*16 + quad*4] = pk.u2;
        }
}

// ---------------- fused: enc3 sigmoid + relation-1 U + T-partial -----------
__global__ __launch_bounds__(256) void k_linfuse0(
    const ushort_t* __restrict__ xin,                 // E2, row-major
    const ushort_t* __restrict__ W3h, const ushort_t* __restrict__ W3l,
    const void* __restrict__ b3,
    const ushort_t* __restrict__ W1h, const ushort_t* __restrict__ W1l,
    const void* __restrict__ b1,
    ushort_t* __restrict__ A, ushort_t* __restrict__ UT,
    float* __restrict__ dvec, ushort_t* __restrict__ Tp,
    const void* __restrict__ detin)
{
    __shared__ __align__(16) ushort_t xs[8192];
    __shared__ __align__(16) ushort_t xt[8192];
    int f32 = detect_dev(detin);
    int t = threadIdx.x;
    size_t row0 = (size_t)blockIdx.x * 64;
    int b = (int)(row0 >> 10), rbase = (int)(row0 & 1023);
    {
        const uint4* src = (const uint4*)(xin + row0*128);
        #pragma unroll
        for (int c = 0; c < 4; c++){
            int i = t + c*256;
            int r = i >> 4, kg = i & 15;
            *(uint4*)&xs[(kg*64 + r)*8] = src[i];
        }
    }
    __syncthreads();
    int w = t >> 6, lane = t & 63;
    int col = lane & 15, quad = lane >> 4;
    v4f acc[4][2];
    #pragma unroll
    for (int m=0;m<4;m++)
        #pragma unroll
        for (int nt=0;nt<2;nt++) acc[m][nt] = (v4f){0.f,0.f,0.f,0.f};
    #pragma unroll
    for (int kt = 0; kt < 4; kt++){
        int kg = kt*4 + quad;
        v8s a[4], bh[2], bl[2];
        #pragma unroll
        for (int nt=0;nt<2;nt++){
            int n = w*32 + nt*16 + col;
            bh[nt] = *(const v8s*)&W3h[(kg*128 + n)*8];
            bl[nt] = *(const v8s*)&W3l[(kg*128 + n)*8];
        }
        #pragma unroll
        for (int m=0;m<4;m++)
            a[m] = *(const v8s*)&xs[(kg*64 + m*16 + col)*8];
        #pragma unroll
        for (int m=0;m<4;m++)
            #pragma unroll
            for (int nt=0;nt<2;nt++){
                acc[m][nt] = MFMA_BF16(a[m], bh[nt], acc[m][nt], 0, 0, 0);
                acc[m][nt] = MFMA_BF16(a[m], bl[nt], acc[m][nt], 0, 0, 0);
            }
    }
    float o[2][16];
    #pragma unroll
    for (int nt=0;nt<2;nt++){
        int n = w*32 + nt*16 + col;
        float bn = ldin(b3, n, f32);
        #pragma unroll
        for (int m=0;m<4;m++)
            #pragma unroll
            for (int reg=0;reg<4;reg++){
                float v = acc[m][nt][reg] + bn;
                o[nt][m*4+reg] = 1.f/(1.f+expf(-v));
            }
    }
    __syncthreads();
    tail_stage_x(xs, xt, o, w, col, quad);
    __syncthreads();
    tail_write_A(xs, A, row0, t);
    tail_lin_relu_T(xs, xt, UT, W1h, W1l, b1, dvec, Tp,
                    row0, b, rbase, t, w, col, quad, f32);
}

// ---------------- reduce 16 bf16 partials -> Tt hi/lo (MFMA-B layout) ------
// thread = (b, cg, n): reads lane-coalesced over n; writes uint4-coalesced.
__global__ __launch_bounds__(256) void k_tredb(const ushort_t* __restrict__ Tp,
                                               ushort_t* __restrict__ Thi, ushort_t* __restrict__ Tlo){
    int tau = blockIdx.x*256 + threadIdx.x;     // 65536 total
    int b = tau >> 11;
    int j2 = tau & 2047;
    int cg = j2 >> 7, n = j2 & 127;
    float sum[8] = {0,0,0,0,0,0,0,0};
    #pragma unroll
    for (int s = 0; s < 16; s++){
        const ushort_t* src = Tp + ((size_t)(s*NB + b) << 14) + cg*8*128 + n;
        #pragma unroll
        for (int cc = 0; cc < 8; cc++)
            sum[cc] += bf2f(src[cc*128]);
    }
    union { uint4 u; ushort_t s[8]; } ph, pl;
    #pragma unroll
    for (int cc = 0; cc < 8; cc++){
        ushort_t h = f2bf(sum[cc]);
        ph.s[cc] = h;
        pl.s[cc] = f2bf(sum[cc] - bf2f(h));
    }
    size_t di = ((size_t)b << 14) + ((size_t)cg*128 + n)*8;
    *(uint4*)&Thi[di] = ph.u;
    *(uint4*)&Tlo[di] = pl.u;
}

// ---------------- fused: relout_r (+ lin_{r+1} + T-partial unless LAST) ----
template<int LAST>
__global__ __launch_bounds__(256) void k_relfuse(
    ushort_t* __restrict__ x, ushort_t* __restrict__ UT,
    const ushort_t* __restrict__ Thi, const ushort_t* __restrict__ Tlo,
    float* __restrict__ dvec,
    const void* __restrict__ psi, const void* __restrict__ phi, const void* __restrict__ wr,
    const ushort_t* __restrict__ Wnh, const ushort_t* __restrict__ Wnl,
    const void* __restrict__ bnext, ushort_t* __restrict__ Tp,
    const void* __restrict__ detin)
{
    __shared__ __align__(16) ushort_t xs[8192];
    __shared__ __align__(16) ushort_t xt[8192];
    int f32 = detect_dev(detin);
    int t = threadIdx.x;
    size_t row0 = (size_t)blockIdx.x * 64;
    int b = (int)(row0 >> 10), rbase = (int)(row0 & 1023);
    {
        const uint4* src = (const uint4*)(x + row0*128);
        #pragma unroll
        for (int c = 0; c < 4; c++){
            int i = t + c*256;
            int r = i >> 4, kg = i & 15;
            *(uint4*)&xs[(kg*64 + r)*8] = src[i];
        }
    }
    __syncthreads();
    float alpha = ldin(wr,0,f32) * ldin(psi,0,f32) * ldin(phi,0,f32) * (1.f/1024.f);
    int w = t >> 6, lane = t & 63;
    int col = lane & 15, quad = lane >> 4;
    const ushort_t* sh = Thi + ((size_t)b << 14);
    const ushort_t* sl = Tlo + ((size_t)b << 14);
    v4f acc[4][2];
    #pragma unroll
    for (int m=0;m<4;m++)
        #pragma unroll
        for (int nt=0;nt<2;nt++) acc[m][nt] = (v4f){0.f,0.f,0.f,0.f};
    #pragma unroll
    for (int kt = 0; kt < 4; kt++){
        int kg = kt*4 + quad;
        v8s a[4], bh[2], bl[2];
        #pragma unroll
        for (int nt=0;nt<2;nt++){
            int n = w*32 + nt*16 + col;
            bh[nt] = *(const v8s*)&sh[(kg*128 + n)*8];
            bl[nt] = *(const v8s*)&sl[(kg*128 + n)*8];
        }
        #pragma unroll
        for (int m=0;m<4;m++)
            a[m] = *(const v8s*)&xs[(kg*64 + m*16 + col)*8];
        #pragma unroll
        for (int m=0;m<4;m++)
            #pragma unroll
            for (int nt=0;nt<2;nt++){
                acc[m][nt] = MFMA_BF16(a[m], bh[nt], acc[m][nt], 0, 0, 0);
                acc[m][nt] = MFMA_BF16(a[m], bl[nt], acc[m][nt], 0, 0, 0);
            }
    }
    float o[2][16];
    #pragma unroll
    for (int m=0;m<4;m++){
        float4 d4 = *(const float4*)&dvec[row0 + m*16 + quad*4];
        const float* dr = (const float*)&d4;
        #pragma unroll
        for (int nt=0;nt<2;nt++){
            int n = w*32 + nt*16 + col;
            uint2 uu = *(const uint2*)&UT[((size_t)b*128 + n)*1024 + rbase + m*16 + quad*4];
            float uf[4];
            uf[0] = __uint_as_float(uu.x << 16);
            uf[1] = __uint_as_float(uu.x & 0xffff0000u);
            uf[2] = __uint_as_float(uu.y << 16);
            uf[3] = __uint_as_float(uu.y & 0xffff0000u);
            #pragma unroll
            for (int reg=0;reg<4;reg++){
                int r = m*16 + quad*4 + reg;
                float xv = bf2f(xs[((n>>3)*64 + r)*8 + (n&7)]);
                o[nt][m*4+reg] = fmaf(alpha, acc[m][nt][reg] - dr[reg]*uf[reg], xv);
            }
        }
    }
    __syncthreads();           // all xs / dvec / UT reads done
    tail_stage_x(xs, xt, o, w, col, quad);
    __syncthreads();
    tail_write_A(xs, x, row0, t);
    if (!LAST)
        tail_lin_relu_T(xs, xt, UT, Wnh, Wnl, bnext, dvec, Tp,
                        row0, b, rbase, t, w, col, quad, f32);
}

// ---------------- decoder tail (512 blocks x 8-tile loop) ------------------
__global__ __launch_bounds__(256) void k_dec2(
    const ushort_t* __restrict__ x,       // [B,N,64]
    const float* __restrict__ W2t, const void* __restrict__ b2,
    const float* __restrict__ Wct, const void* __restrict__ bcb,
    const float* __restrict__ Wgt, const void* __restrict__ bgb,
    void* __restrict__ out, const void* __restrict__ detin)
{
    int f32 = detect_dev(detin);
    __shared__ __align__(16) float w2[64*32];
    __shared__ __align__(16) float wc[32*28];
    __shared__ __align__(16) float wg[32*4];
    __shared__ __align__(16) float xsd[8][64];
    __shared__ float hs[8][33];
    int t = threadIdx.x;
    for (int i=t;i<512;i+=256)  ((float4*)w2)[i] = ((const float4*)W2t)[i];
    if (t < 224) ((float4*)wc)[t] = ((const float4*)Wct)[t];
    if (t < 32)  ((float4*)wg)[t] = ((const float4*)Wgt)[t];
    int j = t & 31, r = t >> 5;
    for (int tile = blockIdx.x; tile < 4096; tile += 512){
        size_t row0 = (size_t)tile * 8;
        __syncthreads();
        if (t < 64){
            int row = t >> 3, seg = t & 7;
            uint4 v = *(const uint4*)&x[(row0 + row)*64 + seg*8];
            float f[8]; unpack8(v, f);
            *(float4*)&xsd[row][seg*8]   = make_float4(f[0],f[1],f[2],f[3]);
            *(float4*)&xsd[row][seg*8+4] = make_float4(f[4],f[5],f[6],f[7]);
        }
        __syncthreads();
        float a = ldin(b2, j, f32);
        #pragma unroll 8
        for (int k=0;k<64;k++) a = fmaf(xsd[r][k], w2[k*32 + j], a);
        hs[r][j] = fmaxf(a, 0.f);
        __syncthreads();
        float o;
        if (j < 28){
            o = ldin(bcb, j, f32);
            #pragma unroll
            for (int k=0;k<32;k++) o = fmaf(hs[r][k], wc[k*28 + j], o);
        } else {
            int jj = j - 28;
            o = ldin(bgb, jj, f32);
            #pragma unroll
            for (int k=0;k<32;k++) o = fmaf(hs[r][k], wg[k*4 + jj], o);
        }
        size_t oi = (row0 + r)*32 + j;
        if (f32) ((float*)out)[oi] = o;
        else     ((ushort_t*)out)[oi] = f2bf(o);
    }
}

// ---------------------------------------------------------------------------
enum { O_E1=0, O_E2=2048, O_D1=10240, O_D2=18432, O_BC=20480, O_BG=21376 };

extern "C" void kernel_launch(void* const* d_in, const int* in_sizes, int n_in,
                              void* d_out, int out_size, void* d_ws, size_t ws_size,
                              hipStream_t stream)
{
    (void)in_sizes; (void)n_in; (void)out_size; (void)ws_size;
    const void* input = d_in[0];
    const void* e1_W = d_in[1];  const void* e1_b = d_in[2];
    const void* bn1_g = d_in[3]; const void* bn1_b = d_in[4];
    const void* e2_W = d_in[5];  const void* e2_b = d_in[6];
    const void* bn2_g = d_in[7]; const void* bn2_b = d_in[8];
    const void* e3_W = d_in[9];  const void* e3_b = d_in[10];
    const void *rW[4], *rb[4], *rpsi[4], *rphi[4], *rwr[4];
    for (int r = 0; r < 4; r++){
        rW[r]   = d_in[11 + r*5 + 0];
        rb[r]   = d_in[11 + r*5 + 1];
        rpsi[r] = d_in[11 + r*5 + 2];
        rphi[r] = d_in[11 + r*5 + 3];
        rwr[r]  = d_in[11 + r*5 + 4];
    }
    const void* d1_W = d_in[31]; const void* d1_b = d_in[32];
    const void* dbn_g = d_in[33];const void* dbn_b = d_in[34];
    const void* d2_W = d_in[35]; const void* d2_b = d_in[36];
    const void* bc_W = d_in[37]; const void* bc_b = d_in[38];
    const void* bg_W = d_in[39]; const void* bg_b = d_in[40];

    // ---- workspace layout (44.6 MB), float offsets (all 16B-aligned) ----
    float*    ws_f = (float*)d_ws;
    float*    wpf  = ws_f;                          // 21504 f
    float*    dd   = ws_f + 21504;                  // 32768 f
    ushort_t* whi  = (ushort_t*)(ws_f + 54272);     // 5*16384 us
    ushort_t* wlo  = (ushort_t*)(ws_f + 95232);     // 5*16384 us
    ushort_t* Thi  = (ushort_t*)(ws_f + 136192);    // 524288 us
    ushort_t* Tlo  = (ushort_t*)(ws_f + 398336);    // 524288 us
    ushort_t* Tp   = (ushort_t*)(ws_f + 660480);    // 16*32*16384 us (bf16!)
    ushort_t* A    = (ushort_t*)(ws_f + 4854784);   // [32768][128] bf16
    ushort_t* UT   = (ushort_t*)(ws_f + 6951936);   // [32][128][1024] bf16
    ushort_t* E2   = (ushort_t*)(ws_f + 9049088);   // [32768][128] bf16
    ushort_t* Cenc = A;                             // [32768][64] overlays A
    ushort_t* Cdec = UT;                            // [32768][64] overlays UT

    PrepArgs pa;
    const void* srcs[11] = {e1_W, e2_W, d1_W, d2_W, bc_W, bg_W,
                            e3_W, rW[0], rW[1], rW[2], rW[3]};
    const int  Ks[11]   = {32,64,128,64,32,32, 128,128,128,128,128};
    const int  Os[11]   = {64,128,64,32,28,4,  128,128,128,128,128};
    const int  offs[11] = {O_E1,O_E2,O_D1,O_D2,O_BC,O_BG, 0,0,0,0,0};
    for (int i=0;i<11;i++){ pa.w[i]=srcs[i]; pa.K[i]=Ks[i]; pa.O[i]=Os[i]; pa.off[i]=offs[i]; }

    k_prep<<<dim3(64,11), 256, 0, stream>>>(pa, wpf, whi, wlo, input);
    k_bnlin<32,64,true><<<512, 128, 0, stream>>>(input, wpf+O_E1, e1_b, bn1_g, bn1_b, Cenc, input);
    k_bnlin<64,128,false><<<512, 128, 0, stream>>>(Cenc, wpf+O_E2, e2_b, bn2_g, bn2_b, E2, input);
    k_linfuse0<<<512, 256, 0, stream>>>(E2, whi, wlo, e3_b,
                                        whi + 16384, wlo + 16384, rb[0],
                                        A, UT, dd, Tp, input);

    for (int r = 0; r < 4; r++){
        k_tredb<<<256, 256, 0, stream>>>(Tp, Thi, Tlo);
        if (r < 3)
            k_relfuse<0><<<512, 256, 0, stream>>>(A, UT, Thi, Tlo, dd,
                rpsi[r], rphi[r], rwr[r],
                whi + (size_t)(2+r)*16384, wlo + (size_t)(2+r)*16384, rb[r+1], Tp, input);
        else
            k_relfuse<1><<<512, 256, 0, stream>>>(A, UT, Thi, Tlo, dd,
                rpsi[r], rphi[r], rwr[r], whi, wlo, rb[r], Tp, input);
    }

    k_bnlin<128,64,false><<<512, 128, 0, stream>>>(A, wpf+O_D1, d1_b, dbn_g, dbn_b, Cdec, input);
    k_dec2<<<512, 256, 0, stream>>>(Cdec, wpf+O_D2, d2_b, wpf+O_BC, bc_b, wpf+O_BG, bg_b, d_out, input);
}